// Round 13
// baseline (150.782 us; speedup 1.0000x reference)
//
#include <hip/hip_runtime.h>
#include <hip/hip_bf16.h>
#include <math.h>
#include <type_traits>

// ---------------------------------------------------------------------------
// Workspace layout (byte offsets). Activations as u8 quant levels q in [0,15];
// f32 value reconstructed EXACTLY as (float)q * (s/15). A3 aliases OUT1B.
// Pre-quantized weights live past OUT2B (float offsets within WQ region).
// ---------------------------------------------------------------------------
constexpr size_t OFF_OUT1B = 0;                          // u8 [256][6][79][80]
constexpr size_t OFF_OUT2B = (size_t)256 * 6 * 79 * 80;  // u8 [256][12][38][40]
constexpr size_t OFF_A3B   = 0;                          // u8 [256][18][18][18]
constexpr size_t OFF_WQ    = OFF_OUT2B + (size_t)256 * 12 * 38 * 40;  // f32 region

// float offsets inside WQ region
constexpr int QW3  = 0;       // 1944
constexpr int QB3  = 1944;    // 18
constexpr int QW4  = 1968;    // 2916
constexpr int QB4  = 4884;    // 18
constexpr int QW5  = 4904;    // 2916
constexpr int QB5  = 7820;    // 18
constexpr int QF1  = 7840;    // 19440 transposed [162][120]
constexpr int QFB1 = 27280;   // 120
constexpr int QF2  = 27400;   // 10080 transposed [120][84]
constexpr int QFB2 = 37480;   // 84
constexpr int QF3  = 37568;   // 756 transposed [84][9]

// ---------------------------------------------------------------------------
// prep: quantize all tail weights/biases ONCE (17 blocks). Block-max is an
// exact order-independent reduction -> scales bit-identical everywhere.
// ---------------------------------------------------------------------------
__device__ float block_max_abs(const float* p, int n, int tid, float* red) {
    float m = 0.0f;
    for (int i = tid; i < n; i += 256) m = fmaxf(m, fabsf(p[i]));
    red[tid] = m;
    __syncthreads();
    for (int s = 128; s > 0; s >>= 1) {
        if (tid < s) red[tid] = fmaxf(red[tid], red[tid + s]);
        __syncthreads();
    }
    const float r = red[0];
    __syncthreads();
    return r;
}

__global__ __launch_bounds__(256)
void prep(const float* __restrict__ w3, const float* __restrict__ b3,
          const float* __restrict__ w4, const float* __restrict__ b4,
          const float* __restrict__ w5, const float* __restrict__ b5,
          const float* __restrict__ fw1, const float* __restrict__ fb1,
          const float* __restrict__ fw2, const float* __restrict__ fb2,
          const float* __restrict__ fw3,
          const float* __restrict__ s2, const float* __restrict__ s3,
          const float* __restrict__ s4, const float* __restrict__ s5,
          const float* __restrict__ s6,
          float* __restrict__ wq)
{
    __shared__ float red[256];
    const int b   = blockIdx.x;
    const int tid = threadIdx.x;

    if (b == 0) {                 // w3 -> QW3
        const float s = block_max_abs(w3, 1944, tid, red) / 3.0f;
        for (int i = tid; i < 1944; i += 256) {
            float q = rintf(w3[i] / s); q = fminf(fmaxf(q, -3.f), 3.f);
            wq[QW3 + i] = q * s;
        }
    } else if (b == 1) {          // w4 -> QW4
        const float s = block_max_abs(w4, 2916, tid, red) / 3.0f;
        for (int i = tid; i < 2916; i += 256) {
            float q = rintf(w4[i] / s); q = fminf(fmaxf(q, -3.f), 3.f);
            wq[QW4 + i] = q * s;
        }
    } else if (b == 2) {          // w5 -> QW5
        const float s = block_max_abs(w5, 2916, tid, red) / 3.0f;
        for (int i = tid; i < 2916; i += 256) {
            float q = rintf(w5[i] / s); q = fminf(fmaxf(q, -3.f), 3.f);
            wq[QW5 + i] = q * s;
        }
    } else if (b <= 10) {         // fw1 slice (b-3)/8 -> QF1 transposed [162][120]
        const float s = block_max_abs(fw1, 19440, tid, red) / 3.0f;
        const int sl = b - 3;
        const int lo = 19440 * sl / 8, hi = 19440 * (sl + 1) / 8;
        for (int i = lo + tid; i < hi; i += 256) {
            const int m = i / 162, k = i - m * 162;
            float q = rintf(fw1[i] / s); q = fminf(fmaxf(q, -3.f), 3.f);
            wq[QF1 + k * 120 + m] = q * s;
        }
    } else if (b <= 14) {         // fw2 slice (b-11)/4 -> QF2 transposed [120][84]
        const float s = block_max_abs(fw2, 10080, tid, red) / 3.0f;
        const int sl = b - 11;
        const int lo = 10080 * sl / 4, hi = 10080 * (sl + 1) / 4;
        for (int i = lo + tid; i < hi; i += 256) {
            const int m = i / 120, k = i - m * 120;
            float q = rintf(fw2[i] / s); q = fminf(fmaxf(q, -3.f), 3.f);
            wq[QF2 + k * 84 + m] = q * s;
        }
    } else if (b == 15) {         // fw3 -> QF3 transposed [84][9]
        const float s = block_max_abs(fw3, 756, tid, red) / 3.0f;
        for (int i = tid; i < 756; i += 256) {
            const int m = i / 84, k = i - m * 84;
            float q = rintf(fw3[i] / s); q = fminf(fmaxf(q, -3.f), 3.f);
            wq[QF3 + k * 9 + m] = q * s;
        }
    } else {                      // b == 16: all biases
        const float s3w = block_max_abs(w3, 1944, tid, red) / 3.0f;
        const float s4w = block_max_abs(w4, 2916, tid, red) / 3.0f;
        const float s5w = block_max_abs(w5, 2916, tid, red) / 3.0f;
        const float sg1 = block_max_abs(fw1, 19440, tid, red) / 3.0f;
        const float sg2 = block_max_abs(fw2, 10080, tid, red) / 3.0f;
        if (tid < 18)  { const float sb = s3w * (s2[0] / 15.f); wq[QB3 + tid]  = rintf(b3[tid] / sb) * sb; }
        if (tid < 18)  { const float sb = s4w * (s3[0] / 15.f); wq[QB4 + tid]  = rintf(b4[tid] / sb) * sb; }
        if (tid < 18)  { const float sb = s5w * (s4[0] / 15.f); wq[QB5 + tid]  = rintf(b5[tid] / sb) * sb; }
        if (tid < 120) { const float sb = sg1 * (s5[0] / 15.f); wq[QFB1 + tid] = rintf(fb1[tid] / sb) * sb; }
        if (tid < 84)  { const float sb = sg2 * (s6[0] / 15.f); wq[QFB2 + tid] = rintf(fb2[tid] / sb) * sb; }
    }
}

// ---------------------------------------------------------------------------
// Fused conv3x3(VALID)[+bias]+quant_relu+maxpool2 (stages 1-2).
// Direct-global reads, 3-deep prefetch ring, in-kernel weight self-quant.
// (Unchanged from R10-R12 — verified.)
// ---------------------------------------------------------------------------
template<int CIN, int COUT, int NCO, int HIN, int WSIN,
         int HPOOL, int WPOOL, int WSOUT, int XG, int RB,
         int THREADS, bool HAS_BIAS, bool IN_U8>
__global__ __launch_bounds__(THREADS)
void conv_stage(const void* __restrict__ in_,
                const float* __restrict__ w_raw,
                const float* __restrict__ b_raw,
                const float* __restrict__ s_prev,
                const float* __restrict__ s_act,
                unsigned char* __restrict__ out)
{
    using TIN = typename std::conditional<IN_U8, unsigned char, float>::type;
    constexpr int GROUPS = COUT / NCO;
    constexpr int W4IN   = WSIN / 4;
    constexpr int NW     = COUT * CIN * 9;
    constexpr int STEPS  = 4 * CIN;
    static_assert(NCO * GROUPS == COUT, "NCO divides COUT");
    static_assert(GROUPS * XG * RB <= THREADS, "single compute pass");
    static_assert(4 * XG == WSOUT, "full padded row coverage");
    static_assert(WSIN % 4 == 0, "vec4 loads");

    __shared__ float lw[NW];
    __shared__ float lb[COUT];
    __shared__ float red[THREADS];

    const int r0  = blockIdx.x * RB;
    const int n   = blockIdx.y;
    const int tid = threadIdx.x;

    float mx = 0.0f;
    for (int i = tid; i < NW; i += THREADS) {
        const float v = w_raw[i];
        lw[i] = v;
        mx = fmaxf(mx, fabsf(v));
    }
    if (HAS_BIAS)
        for (int i = tid; i < COUT; i += THREADS) lb[i] = b_raw[i];
    red[tid] = mx;
    __syncthreads();
    for (int s = THREADS / 2; s > 0; s >>= 1) {
        if (tid < s) red[tid] = fmaxf(red[tid], red[tid + s]);
        __syncthreads();
    }
    const float sw_ = red[0] / 3.0f;
    for (int i = tid; i < NW; i += THREADS) {
        float q = rintf(lw[i] / sw_);
        q = fminf(fmaxf(q, -3.0f), 3.0f);
        lw[i] = q * sw_;
    }
    if (HAS_BIAS) {
        const float sb = sw_ * (s_prev[0] / 15.0f);
        for (int i = tid; i < COUT; i += THREADS)
            lb[i] = rintf(lb[i] / sb) * sb;
    }
    __syncthreads();

    const int o = tid;
    if (o >= GROUPS * XG * RB) return;
    const int cog = o % GROUPS;
    const int xg  = (o / GROUPS) % XG;
    const int ry  = o / (GROUPS * XG);
    const int r   = r0 + ry;
    if (r >= HPOOL) return;

    const float step = s_act[0] / 15.0f;
    float step_in = 0.0f;
    if constexpr (IN_U8) step_in = s_prev[0] / 15.0f;

    const int u0 = 2 * xg;
    const int u1 = 2 * xg + 1;
    const int u2 = (2 * xg + 2 < W4IN) ? (2 * xg + 2) : (W4IN - 1);

    const TIN* in   = (const TIN*)in_;
    const TIN* base = in + (size_t)n * CIN * HIN * WSIN + (size_t)(2 * r) * WSIN;

    float acc[NCO][16];
#pragma unroll
    for (int j = 0; j < NCO; ++j)
#pragma unroll
        for (int i = 0; i < 16; ++i) acc[j][i] = 0.0f;

    float4       fbuf[3][3];
    unsigned int ubuf[3][3];
    float        wv[NCO][9];

#define ISSUE_STEP(S)                                                          \
    {                                                                          \
        const TIN* rp = base + (size_t)((S) >> 2) * HIN * WSIN                 \
                             + (size_t)((S) & 3) * WSIN;                       \
        if constexpr (IN_U8) {                                                 \
            ubuf[(S) % 3][0] = *(const unsigned int*)&rp[4 * u0];              \
            ubuf[(S) % 3][1] = *(const unsigned int*)&rp[4 * u1];              \
            ubuf[(S) % 3][2] = *(const unsigned int*)&rp[4 * u2];              \
        } else {                                                               \
            fbuf[(S) % 3][0] = *(const float4*)&rp[4 * u0];                    \
            fbuf[(S) % 3][1] = *(const float4*)&rp[4 * u1];                    \
            fbuf[(S) % 3][2] = *(const float4*)&rp[4 * u2];                    \
        }                                                                      \
    }

    ISSUE_STEP(0);
    ISSUE_STEP(1);

#pragma unroll
    for (int s = 0; s < STEPS; ++s) {
        const int c  = s >> 2;
        const int rr = s & 3;

        if (s + 2 < STEPS) ISSUE_STEP(s + 2);

        if (rr == 0) {
#pragma unroll
            for (int j = 0; j < NCO; ++j)
#pragma unroll
                for (int k = 0; k < 9; ++k)
                    wv[j][k] = lw[((NCO * cog + j) * CIN + c) * 9 + k];
        }

        float row[12];
        if constexpr (IN_U8) {
#pragma unroll
            for (int k = 0; k < 3; ++k) {
                const unsigned int d = ubuf[s % 3][k];
#pragma unroll
                for (int b = 0; b < 4; ++b)
                    row[4 * k + b] = (float)((d >> (8 * b)) & 0xffu) * step_in;
            }
        } else {
            const float* rv = (const float*)fbuf[s % 3];
#pragma unroll
            for (int i = 0; i < 12; ++i) row[i] = rv[i];
        }

        if (rr < 3) {
#pragma unroll
            for (int j = 0; j < NCO; ++j)
#pragma unroll
                for (int kc = 0; kc < 3; ++kc)
#pragma unroll
                    for (int xx = 0; xx < 8; ++xx)
                        acc[j][xx] = fmaf(row[xx + kc], wv[j][rr * 3 + kc], acc[j][xx]);
        }
        if (rr >= 1) {
#pragma unroll
            for (int j = 0; j < NCO; ++j)
#pragma unroll
                for (int kc = 0; kc < 3; ++kc)
#pragma unroll
                    for (int xx = 0; xx < 8; ++xx)
                        acc[j][8 + xx] = fmaf(row[xx + kc], wv[j][(rr - 1) * 3 + kc], acc[j][8 + xx]);
        }
    }
#undef ISSUE_STEP

#pragma unroll
    for (int j = 0; j < NCO; ++j) {
        const int co = NCO * cog + j;
        const float bias = HAS_BIAS ? lb[co] : 0.0f;
        unsigned int pck = 0;
#pragma unroll
        for (int t = 0; t < 4; ++t) {
            float m = fmaxf(fmaxf(acc[j][2 * t], acc[j][2 * t + 1]),
                            fmaxf(acc[j][8 + 2 * t], acc[j][8 + 2 * t + 1]));
            float v = fmaxf(m + bias, 0.0f);
            float q = rintf(v / step);
            q = fminf(fmaxf(q, 0.0f), 15.0f);
            const unsigned int qi = (4 * xg + t < WPOOL) ? (unsigned int)q : 0u;
            pck |= qi << (8 * t);
        }
        *(unsigned int*)&out[(((size_t)n * COUT + co) * HPOOL + r) * WSOUT + 4 * xg] = pck;
    }
}

// ---------------------------------------------------------------------------
// Stage 3: u8 [12][38][40] -> u8 A3 [18][18][18]. Headless (pre-quantized
// weights), direct-global 16B row loads (memcpy -> dwordx4; worst case the
// compiler splits to dwords = previous behavior). Output u8 levels (exact).
// ---------------------------------------------------------------------------
__global__ __launch_bounds__(512)
void conv3_stage(const unsigned char* __restrict__ in2,  // u8 [256][12][38][40]
                 const float* __restrict__ wq,
                 const float* __restrict__ s2, const float* __restrict__ s3,
                 unsigned char* __restrict__ a3u)        // u8 [256][18][18][18]
{
    __shared__ float lw[1944];
    __shared__ float lb[18];

    const int rb  = blockIdx.x;           // 0/1: pooled rows 9*rb..9*rb+8
    const int n   = blockIdx.y;
    const int tid = threadIdx.x;

    for (int i = tid; i < 1944; i += 512) lw[i] = wq[QW3 + i];
    if (tid < 18) lb[tid] = wq[QB3 + tid];
    __syncthreads();

    if (tid >= 486) return;               // 9 rows x 18 co x 3 thirds
    const int rloc = tid / 54;
    const int rm   = tid - rloc * 54;
    const int co   = rm / 3;
    const int th   = rm - co * 3;         // pooled x in [6*th, 6*th+6)
    const int r    = rb * 9 + rloc;

    const float step2 = s2[0] / 15.0f;
    const float st    = s3[0] / 15.0f;

    const unsigned char* base = in2 + (size_t)n * 18240 + (size_t)(2 * r) * 40 + 12 * th;

    float acc0[12], acc1[12];
#pragma unroll
    for (int i = 0; i < 12; ++i) { acc0[i] = 0.f; acc1[i] = 0.f; }

    uint4 ub[2][4];                       // ping-pong: 4 rows x 16 bytes

#define LOADC(C, B)                                                            \
    {                                                                          \
        const unsigned char* cp = base + (size_t)(C) * 1520;                   \
        _Pragma("unroll")                                                      \
        for (int rr = 0; rr < 4; ++rr)                                         \
            __builtin_memcpy(&ub[B][rr], cp + rr * 40, 16);                    \
    }

    LOADC(0, 0);

#pragma unroll
    for (int c = 0; c < 12; ++c) {
        if (c + 1 < 12) LOADC(c + 1, (c + 1) & 1);

        float wv[9];
#pragma unroll
        for (int k = 0; k < 9; ++k) wv[k] = lw[(co * 12 + c) * 9 + k];

#pragma unroll
        for (int rr = 0; rr < 4; ++rr) {
            const unsigned int* dp = (const unsigned int*)&ub[c & 1][rr];
            float row[16];
#pragma unroll
            for (int k = 0; k < 4; ++k) {
                const unsigned int d = dp[k];
#pragma unroll
                for (int b = 0; b < 4; ++b)
                    row[4 * k + b] = (float)((d >> (8 * b)) & 0xffu) * step2;
            }
            if (rr < 3) {
#pragma unroll
                for (int kc = 0; kc < 3; ++kc)
#pragma unroll
                    for (int xx = 0; xx < 12; ++xx)
                        acc0[xx] = fmaf(row[xx + kc], wv[rr * 3 + kc], acc0[xx]);
            }
            if (rr >= 1) {
#pragma unroll
                for (int kc = 0; kc < 3; ++kc)
#pragma unroll
                    for (int xx = 0; xx < 12; ++xx)
                        acc1[xx] = fmaf(row[xx + kc], wv[(rr - 1) * 3 + kc], acc1[xx]);
            }
        }
    }
#undef LOADC

    const float bias = lb[co];
    unsigned char* orow = a3u + (size_t)n * 5832 + (size_t)co * 324 + (size_t)r * 18 + 6 * th;
#pragma unroll
    for (int x = 0; x < 6; ++x) {
        float m = fmaxf(fmaxf(acc0[2 * x], acc0[2 * x + 1]),
                        fmaxf(acc1[2 * x], acc1[2 * x + 1]));
        float v = fmaxf(m + bias, 0.0f);
        float q = rintf(v / st);
        q = fminf(fmaxf(q, 0.0f), 15.0f);
        orow[x] = (unsigned char)q;
    }
}

// ---------------------------------------------------------------------------
// Tail: stage4 + stage5 + fc1/fc2/fc3, one 1024-thread block per image.
// Headless (pre-quantized weights). A3 in LDS padded to stride 20 (<=2-way
// bank aliasing, free). O4 transposed stride 19. FCs: clean fma loops on
// transposed pre-quantized weights, split-k.
// ---------------------------------------------------------------------------
__global__ __launch_bounds__(1024)
void tail456(const unsigned char* __restrict__ a3u,    // u8 [256][18][18][18]
             const float* __restrict__ wq,
             const float* __restrict__ s3, const float* __restrict__ s4,
             const float* __restrict__ s5, const float* __restrict__ s6,
             const float* __restrict__ s7,
             float* __restrict__ out)
{
    __shared__ float A3f[18 * 18 * 20];   // padded x-stride 20
    __shared__ float W4q[2916], W5q[2916];
    __shared__ float B4q[18], B5q[18];
    __shared__ float O4t[64 * 19 + 1];    // (rx)*19 + co
    __shared__ float A5[162], A6[120], A7[84];
    __shared__ float part[8][120];

    const int n   = blockIdx.x;
    const int tid = threadIdx.x;

    // ---- phase 0: u8 slab -> padded f32 LDS (dequant once), weight copies ----
    const float st3 = s3[0] / 15.0f;
    {
        const unsigned int* src = (const unsigned int*)(a3u + (size_t)n * 5832);
        for (int i = tid; i < 1458; i += 1024) {
            const unsigned int d = src[i];
#pragma unroll
            for (int b = 0; b < 4; ++b) {
                const int idx = 4 * i + b;           // = co*324 + r*18 + x
                const int co  = idx / 324;
                const int rem = idx - co * 324;
                const int r   = rem / 18;
                const int x   = rem - r * 18;
                A3f[(co * 18 + r) * 20 + x] = (float)((d >> (8 * b)) & 0xffu) * st3;
            }
        }
    }
    for (int i = tid; i < 2916; i += 1024) W4q[i] = wq[QW4 + i];
    for (int i = tid; i < 2916; i += 1024) W5q[i] = wq[QW5 + i];
    if (tid < 18) { B4q[tid] = wq[QB4 + tid]; B5q[tid] = wq[QB5 + tid]; }
    __syncthreads();

    // ---- stage4: [18,18,18]->[18,8,8] into transposed O4t ----
    {
        const float st = s4[0] / 15.0f;
        for (int o = tid; o < 1152; o += 1024) {
            const int co = o >> 6;
            const int r  = (o >> 3) & 7;
            const int x  = o & 7;
            float a00 = 0.f, a01 = 0.f, a10 = 0.f, a11 = 0.f;
            for (int c = 0; c < 18; ++c) {
                float win[4][4];
#pragma unroll
                for (int rr = 0; rr < 4; ++rr) {
                    const int base = (c * 18 + 2 * r + rr) * 20 + 2 * x;
                    *(float2*)&win[rr][0] = *(const float2*)&A3f[base];
                    *(float2*)&win[rr][2] = *(const float2*)&A3f[base + 2];
                }
                const float* wp = &W4q[(co * 18 + c) * 9];
#pragma unroll
                for (int kr = 0; kr < 3; ++kr)
#pragma unroll
                    for (int kc = 0; kc < 3; ++kc) {
                        const float wvv = wp[kr * 3 + kc];
                        a00 = fmaf(win[kr    ][kc    ], wvv, a00);
                        a01 = fmaf(win[kr    ][kc + 1], wvv, a01);
                        a10 = fmaf(win[kr + 1][kc    ], wvv, a10);
                        a11 = fmaf(win[kr + 1][kc + 1], wvv, a11);
                    }
            }
            float m = fmaxf(fmaxf(a00, a01), fmaxf(a10, a11));
            float v = fmaxf(m + B4q[co], 0.0f);
            float q = rintf(v / st);
            q = fminf(fmaxf(q, 0.0f), 15.0f);
            O4t[(r * 8 + x) * 19 + co] = q * st;
        }
    }
    __syncthreads();

    // ---- stage5: [18,8,8]->[18,3,3] = A5[162] ----
    {
        const float st = s5[0] / 15.0f;
        if (tid < 162) {
            const int co  = tid / 9;
            const int rem = tid - co * 9;
            const int r   = rem / 3;
            const int x   = rem - r * 3;
            float a00 = 0.f, a01 = 0.f, a10 = 0.f, a11 = 0.f;
            for (int c = 0; c < 18; ++c) {
                float win[4][4];
#pragma unroll
                for (int rr = 0; rr < 4; ++rr)
#pragma unroll
                    for (int cc = 0; cc < 4; ++cc)
                        win[rr][cc] = O4t[((2 * r + rr) * 8 + 2 * x + cc) * 19 + c];
                const float* wp = &W5q[(co * 18 + c) * 9];
#pragma unroll
                for (int kr = 0; kr < 3; ++kr)
#pragma unroll
                    for (int kc = 0; kc < 3; ++kc) {
                        const float wvv = wp[kr * 3 + kc];
                        a00 = fmaf(win[kr    ][kc    ], wvv, a00);
                        a01 = fmaf(win[kr    ][kc + 1], wvv, a01);
                        a10 = fmaf(win[kr + 1][kc    ], wvv, a10);
                        a11 = fmaf(win[kr + 1][kc + 1], wvv, a11);
                    }
            }
            float m = fmaxf(fmaxf(a00, a01), fmaxf(a10, a11));
            float v = fmaxf(m + B5q[co], 0.0f);
            float q = rintf(v / st);
            q = fminf(fmaxf(q, 0.0f), 15.0f);
            A5[tid] = q * st;
        }
    }
    __syncthreads();

    // ---- fc1: [162]->[120], split-k over 8 chunks, pre-quantized weights ----
    {
        const float* F1 = wq + QF1;       // [162][120]
        if (tid < 960) {
            const int m  = tid % 120;
            const int ch = tid / 120;
            const int k0 = 21 * ch;
            const int k1 = (ch == 7) ? 162 : k0 + 21;
            float p = 0.f;
            for (int k = k0; k < k1; ++k)
                p = fmaf(A5[k], F1[k * 120 + m], p);
            part[ch][m] = p;
        }
    }
    __syncthreads();
    if (tid < 120) {
        float acc = part[0][tid];
#pragma unroll
        for (int ch = 1; ch < 8; ++ch) acc += part[ch][tid];
        acc += wq[QFB1 + tid];
        const float st = s6[0] / 15.0f;
        float q = rintf(fmaxf(acc, 0.0f) / st);
        q = fminf(fmaxf(q, 0.0f), 15.0f);
        A6[tid] = q * st;
    }
    __syncthreads();

    // ---- fc2: [120]->[84], split-k over 8 chunks of 15 ----
    {
        const float* F2 = wq + QF2;       // [120][84]
        if (tid < 672) {
            const int m  = tid % 84;
            const int ch = tid / 84;
            const int k0 = 15 * ch;
            float p = 0.f;
            for (int k = k0; k < k0 + 15; ++k)
                p = fmaf(A6[k], F2[k * 84 + m], p);
            part[ch][m] = p;
        }
    }
    __syncthreads();
    if (tid < 84) {
        float acc = part[0][tid];
#pragma unroll
        for (int ch = 1; ch < 8; ++ch) acc += part[ch][tid];
        acc += wq[QFB2 + tid];
        const float st = s7[0] / 15.0f;
        float q = rintf(fmaxf(acc, 0.0f) / st);
        q = fminf(fmaxf(q, 0.0f), 15.0f);
        A7[tid] = q * st;
    }
    __syncthreads();

    // ---- fc3: [9 x 84], split-k over 7 chunks of 12 ----
    {
        const float* F3 = wq + QF3;       // [84][9]
        if (tid < 63) {
            const int m  = tid % 9;
            const int ch = tid / 9;
            const int k0 = 12 * ch;
            float p = 0.f;
            for (int k = k0; k < k0 + 12; ++k)
                p = fmaf(A7[k], F3[k * 9 + m], p);
            part[ch][m] = p;
        }
    }
    __syncthreads();
    if (tid < 9) {
        float acc = part[0][tid];
#pragma unroll
        for (int ch = 1; ch < 7; ++ch) acc += part[ch][tid];
        out[(size_t)n * 9 + tid] = acc;
    }
}

// ---------------------------------------------------------------------------
extern "C" void kernel_launch(void* const* d_in, const int* in_sizes, int n_in,
                              void* d_out, int out_size, void* d_ws, size_t ws_size,
                              hipStream_t stream)
{
    const float* x   = (const float*)d_in[0];
    const float* w1  = (const float*)d_in[1];
    const float* w2  = (const float*)d_in[2];
    const float* b2  = (const float*)d_in[3];
    const float* w3  = (const float*)d_in[4];
    const float* b3  = (const float*)d_in[5];
    const float* w4  = (const float*)d_in[6];
    const float* b4  = (const float*)d_in[7];
    const float* w5  = (const float*)d_in[8];
    const float* b5  = (const float*)d_in[9];
    const float* fw1 = (const float*)d_in[10];
    const float* fb1 = (const float*)d_in[11];
    const float* fw2 = (const float*)d_in[12];
    const float* fb2 = (const float*)d_in[13];
    const float* fw3 = (const float*)d_in[14];
    const float* s1  = (const float*)d_in[15];
    const float* s2  = (const float*)d_in[16];
    const float* s3  = (const float*)d_in[17];
    const float* s4  = (const float*)d_in[18];
    const float* s5  = (const float*)d_in[19];
    const float* s6  = (const float*)d_in[20];
    const float* s7  = (const float*)d_in[21];

    unsigned char* wsb = (unsigned char*)d_ws;
    float* wq = (float*)(wsb + OFF_WQ);
    float* out = (float*)d_out;

    // prep: quantize all tail weights/biases once (17 blocks, ~2-3 us)
    prep<<<17, 256, 0, stream>>>(w3, b3, w4, b4, w5, b5,
                                 fw1, fb1, fw2, fb2, fw3,
                                 s2, s3, s4, s5, s6, wq);

    // stage 1: f32 in -> u8 levels out [256][6][79][80]
    conv_stage<3, 6, 2, 160, 160, 79, 79, 80, 20, 4, 256, false, false>
        <<<dim3(20, 256), 256, 0, stream>>>(x, w1, nullptr, nullptr, s1,
                                            wsb + OFF_OUT1B);

    // stage 2: u8 in -> u8 levels out [256][12][38][40]
    conv_stage<6, 12, 2, 79, 80, 38, 38, 40, 10, 4, 256, true, true>
        <<<dim3(10, 256), 256, 0, stream>>>(wsb + OFF_OUT1B, w2, b2, s1, s2,
                                            wsb + OFF_OUT2B);

    // stage 3: u8 -> u8 A3 (aliases OUT1B), headless, 16B loads
    conv3_stage<<<dim3(2, 256), 512, 0, stream>>>(wsb + OFF_OUT2B, wq, s2, s3,
                                                  wsb + OFF_A3B);

    // stage4+5+fc, one 1024-thread block per image, headless
    tail456<<<256, 1024, 0, stream>>>(wsb + OFF_A3B, wq,
                                      s3, s4, s5, s6, s7, out);
}

// Round 14
// 133.698 us; speedup vs baseline: 1.1278x; 1.1278x over previous
//
#include <hip/hip_runtime.h>
#include <hip/hip_bf16.h>
#include <math.h>
#include <type_traits>

// ---------------------------------------------------------------------------
// Workspace layout (byte offsets). Activations as u8 quant levels q in [0,15];
// f32 value reconstructed EXACTLY as (float)q * (s/15).
// ---------------------------------------------------------------------------
constexpr size_t OFF_OUT1B = 0;                          // u8 [256][6][79][80]
constexpr size_t OFF_OUT2B = (size_t)256 * 6 * 79 * 80;  // u8 [256][12][38][40]

// ---------------------------------------------------------------------------
// Fused conv3x3(VALID)[+bias]+quant_relu+maxpool2 (stages 1-2).
// Direct-global reads, 3-deep prefetch ring, in-kernel weight self-quant.
// (Byte-identical to R12 — verified at s1~58, s2~12.)
// ---------------------------------------------------------------------------
template<int CIN, int COUT, int NCO, int HIN, int WSIN,
         int HPOOL, int WPOOL, int WSOUT, int XG, int RB,
         int THREADS, bool HAS_BIAS, bool IN_U8>
__global__ __launch_bounds__(THREADS)
void conv_stage(const void* __restrict__ in_,
                const float* __restrict__ w_raw,
                const float* __restrict__ b_raw,
                const float* __restrict__ s_prev,
                const float* __restrict__ s_act,
                unsigned char* __restrict__ out)
{
    using TIN = typename std::conditional<IN_U8, unsigned char, float>::type;
    constexpr int GROUPS = COUT / NCO;
    constexpr int W4IN   = WSIN / 4;
    constexpr int NW     = COUT * CIN * 9;
    constexpr int STEPS  = 4 * CIN;
    static_assert(NCO * GROUPS == COUT, "NCO divides COUT");
    static_assert(GROUPS * XG * RB <= THREADS, "single compute pass");
    static_assert(4 * XG == WSOUT, "full padded row coverage");
    static_assert(WSIN % 4 == 0, "vec4 loads");

    __shared__ float lw[NW];
    __shared__ float lb[COUT];
    __shared__ float red[THREADS];

    const int r0  = blockIdx.x * RB;
    const int n   = blockIdx.y;
    const int tid = threadIdx.x;

    float mx = 0.0f;
    for (int i = tid; i < NW; i += THREADS) {
        const float v = w_raw[i];
        lw[i] = v;
        mx = fmaxf(mx, fabsf(v));
    }
    if (HAS_BIAS)
        for (int i = tid; i < COUT; i += THREADS) lb[i] = b_raw[i];
    red[tid] = mx;
    __syncthreads();
    for (int s = THREADS / 2; s > 0; s >>= 1) {
        if (tid < s) red[tid] = fmaxf(red[tid], red[tid + s]);
        __syncthreads();
    }
    const float sw_ = red[0] / 3.0f;
    for (int i = tid; i < NW; i += THREADS) {
        float q = rintf(lw[i] / sw_);
        q = fminf(fmaxf(q, -3.0f), 3.0f);
        lw[i] = q * sw_;
    }
    if (HAS_BIAS) {
        const float sb = sw_ * (s_prev[0] / 15.0f);
        for (int i = tid; i < COUT; i += THREADS)
            lb[i] = rintf(lb[i] / sb) * sb;
    }
    __syncthreads();

    const int o = tid;
    if (o >= GROUPS * XG * RB) return;
    const int cog = o % GROUPS;
    const int xg  = (o / GROUPS) % XG;
    const int ry  = o / (GROUPS * XG);
    const int r   = r0 + ry;
    if (r >= HPOOL) return;

    const float step = s_act[0] / 15.0f;
    float step_in = 0.0f;
    if constexpr (IN_U8) step_in = s_prev[0] / 15.0f;

    const int u0 = 2 * xg;
    const int u1 = 2 * xg + 1;
    const int u2 = (2 * xg + 2 < W4IN) ? (2 * xg + 2) : (W4IN - 1);

    const TIN* in   = (const TIN*)in_;
    const TIN* base = in + (size_t)n * CIN * HIN * WSIN + (size_t)(2 * r) * WSIN;

    float acc[NCO][16];
#pragma unroll
    for (int j = 0; j < NCO; ++j)
#pragma unroll
        for (int i = 0; i < 16; ++i) acc[j][i] = 0.0f;

    float4       fbuf[3][3];
    unsigned int ubuf[3][3];
    float        wv[NCO][9];

#define ISSUE_STEP(S)                                                          \
    {                                                                          \
        const TIN* rp = base + (size_t)((S) >> 2) * HIN * WSIN                 \
                             + (size_t)((S) & 3) * WSIN;                       \
        if constexpr (IN_U8) {                                                 \
            ubuf[(S) % 3][0] = *(const unsigned int*)&rp[4 * u0];              \
            ubuf[(S) % 3][1] = *(const unsigned int*)&rp[4 * u1];              \
            ubuf[(S) % 3][2] = *(const unsigned int*)&rp[4 * u2];              \
        } else {                                                               \
            fbuf[(S) % 3][0] = *(const float4*)&rp[4 * u0];                    \
            fbuf[(S) % 3][1] = *(const float4*)&rp[4 * u1];                    \
            fbuf[(S) % 3][2] = *(const float4*)&rp[4 * u2];                    \
        }                                                                      \
    }

    ISSUE_STEP(0);
    ISSUE_STEP(1);

#pragma unroll
    for (int s = 0; s < STEPS; ++s) {
        const int c  = s >> 2;
        const int rr = s & 3;

        if (s + 2 < STEPS) ISSUE_STEP(s + 2);

        if (rr == 0) {
#pragma unroll
            for (int j = 0; j < NCO; ++j)
#pragma unroll
                for (int k = 0; k < 9; ++k)
                    wv[j][k] = lw[((NCO * cog + j) * CIN + c) * 9 + k];
        }

        float row[12];
        if constexpr (IN_U8) {
#pragma unroll
            for (int k = 0; k < 3; ++k) {
                const unsigned int d = ubuf[s % 3][k];
#pragma unroll
                for (int b = 0; b < 4; ++b)
                    row[4 * k + b] = (float)((d >> (8 * b)) & 0xffu) * step_in;
            }
        } else {
            const float* rv = (const float*)fbuf[s % 3];
#pragma unroll
            for (int i = 0; i < 12; ++i) row[i] = rv[i];
        }

        if (rr < 3) {
#pragma unroll
            for (int j = 0; j < NCO; ++j)
#pragma unroll
                for (int kc = 0; kc < 3; ++kc)
#pragma unroll
                    for (int xx = 0; xx < 8; ++xx)
                        acc[j][xx] = fmaf(row[xx + kc], wv[j][rr * 3 + kc], acc[j][xx]);
        }
        if (rr >= 1) {
#pragma unroll
            for (int j = 0; j < NCO; ++j)
#pragma unroll
                for (int kc = 0; kc < 3; ++kc)
#pragma unroll
                    for (int xx = 0; xx < 8; ++xx)
                        acc[j][8 + xx] = fmaf(row[xx + kc], wv[j][(rr - 1) * 3 + kc], acc[j][8 + xx]);
        }
    }
#undef ISSUE_STEP

#pragma unroll
    for (int j = 0; j < NCO; ++j) {
        const int co = NCO * cog + j;
        const float bias = HAS_BIAS ? lb[co] : 0.0f;
        unsigned int pck = 0;
#pragma unroll
        for (int t = 0; t < 4; ++t) {
            float m = fmaxf(fmaxf(acc[j][2 * t], acc[j][2 * t + 1]),
                            fmaxf(acc[j][8 + 2 * t], acc[j][8 + 2 * t + 1]));
            float v = fmaxf(m + bias, 0.0f);
            float q = rintf(v / step);
            q = fminf(fmaxf(q, 0.0f), 15.0f);
            const unsigned int qi = (4 * xg + t < WPOOL) ? (unsigned int)q : 0u;
            pck |= qi << (8 * t);
        }
        *(unsigned int*)&out[(((size_t)n * COUT + co) * HPOOL + r) * WSOUT + 4 * xg] = pck;
    }
}

__device__ __forceinline__ float wave_max(float v) {
#pragma unroll
    for (int off = 32; off > 0; off >>= 1)
        v = fmaxf(v, __shfl_down(v, off));
    return v;
}

// ---------------------------------------------------------------------------
// tail_all: conv3 + stage4 + stage5 + fc1/fc2/fc3 in ONE kernel,
// one 1024-thread block per image. conv3 reads u8 OUT2 directly from global
// (L2/L3-resident) and writes its output STRAIGHT into the padded A3f LDS —
// no A3 global round-trip, no extra launches. Weight self-quant via wave_max
// (exact order-independent max -> bit-identical scales). O4 transposed
// stride 19 (conflict-free stage5); A3f padded stride 20; split-k FCs with
// on-the-fly fc weight quant (R12-verified numerics).
// ---------------------------------------------------------------------------
__global__ __launch_bounds__(1024)
void tail_all(const unsigned char* __restrict__ in2,   // u8 [256][12][38][40]
              const float* __restrict__ w3, const float* __restrict__ b3,
              const float* __restrict__ w4, const float* __restrict__ b4,
              const float* __restrict__ w5, const float* __restrict__ b5,
              const float* __restrict__ fw1, const float* __restrict__ fb1,
              const float* __restrict__ fw2, const float* __restrict__ fb2,
              const float* __restrict__ fw3,
              const float* __restrict__ s2, const float* __restrict__ s3,
              const float* __restrict__ s4, const float* __restrict__ s5,
              const float* __restrict__ s6, const float* __restrict__ s7,
              float* __restrict__ out)
{
    __shared__ float A3f[18 * 18 * 20];   // padded x-stride 20 (25.9 KB)
    __shared__ float W3q[1944], W4q[2916], W5q[2916];
    __shared__ float B3q[18], B4q[18], B5q[18];
    __shared__ float O4t[64 * 19 + 1];    // (r*8+x)*19 + co
    __shared__ float A5[162], A6[120], A7[84];
    __shared__ float part[8][120];
    __shared__ float sm[16][6];
    __shared__ float scales[6];

    const int n    = blockIdx.x;
    const int tid  = threadIdx.x;
    const int wid  = tid >> 6;
    const int lane = tid & 63;

    // ---- phase 0: weights to LDS + all max-abs scales (wave_max reduce) ----
    float m3 = 0.f, m4 = 0.f, m5 = 0.f, g1 = 0.f, g2 = 0.f, g3 = 0.f;
    for (int i = tid; i < 1944; i += 1024) { const float v = w3[i]; W3q[i] = v; m3 = fmaxf(m3, fabsf(v)); }
    for (int i = tid; i < 2916; i += 1024) { const float v = w4[i]; W4q[i] = v; m4 = fmaxf(m4, fabsf(v)); }
    for (int i = tid; i < 2916; i += 1024) { const float v = w5[i]; W5q[i] = v; m5 = fmaxf(m5, fabsf(v)); }
    {
        const float4* f1 = (const float4*)fw1;
        for (int i = tid; i < 4860; i += 1024) {
            const float4 v = f1[i];
            g1 = fmaxf(g1, fmaxf(fmaxf(fabsf(v.x), fabsf(v.y)), fmaxf(fabsf(v.z), fabsf(v.w))));
        }
        const float4* f2 = (const float4*)fw2;
        for (int i = tid; i < 2520; i += 1024) {
            const float4 v = f2[i];
            g2 = fmaxf(g2, fmaxf(fmaxf(fabsf(v.x), fabsf(v.y)), fmaxf(fabsf(v.z), fabsf(v.w))));
        }
        const float4* f3 = (const float4*)fw3;
        for (int i = tid; i < 189; i += 1024) {
            const float4 v = f3[i];
            g3 = fmaxf(g3, fmaxf(fmaxf(fabsf(v.x), fabsf(v.y)), fmaxf(fabsf(v.z), fabsf(v.w))));
        }
    }
    if (tid < 18) { B3q[tid] = b3[tid]; B4q[tid] = b4[tid]; B5q[tid] = b5[tid]; }
    m3 = wave_max(m3); m4 = wave_max(m4); m5 = wave_max(m5);
    g1 = wave_max(g1); g2 = wave_max(g2); g3 = wave_max(g3);
    if (lane == 0) {
        sm[wid][0] = m3; sm[wid][1] = m4; sm[wid][2] = m5;
        sm[wid][3] = g1; sm[wid][4] = g2; sm[wid][5] = g3;
    }
    __syncthreads();
    if (tid < 6) {
        float v = sm[0][tid];
#pragma unroll
        for (int w = 1; w < 16; ++w) v = fmaxf(v, sm[w][tid]);
        scales[tid] = v / 3.0f;
    }
    __syncthreads();
    const float sw3 = scales[0], sw4 = scales[1], sw5 = scales[2];
    const float sf1 = scales[3], sf2 = scales[4], sf3 = scales[5];

    for (int i = tid; i < 1944; i += 1024) { float q = rintf(W3q[i] / sw3); q = fminf(fmaxf(q, -3.f), 3.f); W3q[i] = q * sw3; }
    for (int i = tid; i < 2916; i += 1024) { float q = rintf(W4q[i] / sw4); q = fminf(fmaxf(q, -3.f), 3.f); W4q[i] = q * sw4; }
    for (int i = tid; i < 2916; i += 1024) { float q = rintf(W5q[i] / sw5); q = fminf(fmaxf(q, -3.f), 3.f); W5q[i] = q * sw5; }
    if (tid < 18) {
        const float sb3 = sw3 * (s2[0] / 15.0f); B3q[tid] = rintf(B3q[tid] / sb3) * sb3;
        const float sb4 = sw4 * (s3[0] / 15.0f); B4q[tid] = rintf(B4q[tid] / sb4) * sb4;
        const float sb5 = sw5 * (s4[0] / 15.0f); B5q[tid] = rintf(B5q[tid] / sb5) * sb5;
    }
    __syncthreads();

    // ---- phase 1: conv3 [12,38,38]->[18,18,18] straight into padded A3f ----
    if (tid < 972) {                       // 18 rows x 18 co x 3 thirds
        const int r  = tid / 54;
        const int rm = tid - r * 54;
        const int co = rm / 3;
        const int th = rm - co * 3;        // pooled x in [6*th, 6*th+6)

        const float step2 = s2[0] / 15.0f;
        const float st3   = s3[0] / 15.0f;
        const unsigned char* base = in2 + (size_t)n * 18240 + (size_t)(2 * r) * 40 + 12 * th;

        float acc0[12], acc1[12];
#pragma unroll
        for (int i = 0; i < 12; ++i) { acc0[i] = 0.f; acc1[i] = 0.f; }

        uint4 ub[2][4];                    // ping-pong: 4 rows x 16 bytes

#define LOADC(C, B)                                                            \
        {                                                                      \
            const unsigned char* cp = base + (size_t)(C) * 1520;               \
            _Pragma("unroll")                                                  \
            for (int rr = 0; rr < 4; ++rr)                                     \
                __builtin_memcpy(&ub[B][rr], cp + rr * 40, 16);                \
        }

        LOADC(0, 0);

#pragma unroll
        for (int c = 0; c < 12; ++c) {
            if (c + 1 < 12) LOADC(c + 1, (c + 1) & 1);

            float wv[9];
#pragma unroll
            for (int k = 0; k < 9; ++k) wv[k] = W3q[(co * 12 + c) * 9 + k];

#pragma unroll
            for (int rr = 0; rr < 4; ++rr) {
                const unsigned int* dp = (const unsigned int*)&ub[c & 1][rr];
                float row[16];
#pragma unroll
                for (int k = 0; k < 4; ++k) {
                    const unsigned int d = dp[k];
#pragma unroll
                    for (int b = 0; b < 4; ++b)
                        row[4 * k + b] = (float)((d >> (8 * b)) & 0xffu) * step2;
                }
                if (rr < 3) {
#pragma unroll
                    for (int kc = 0; kc < 3; ++kc)
#pragma unroll
                        for (int xx = 0; xx < 12; ++xx)
                            acc0[xx] = fmaf(row[xx + kc], wv[rr * 3 + kc], acc0[xx]);
                }
                if (rr >= 1) {
#pragma unroll
                    for (int kc = 0; kc < 3; ++kc)
#pragma unroll
                        for (int xx = 0; xx < 12; ++xx)
                            acc1[xx] = fmaf(row[xx + kc], wv[(rr - 1) * 3 + kc], acc1[xx]);
                }
            }
        }
#undef LOADC

        const float bias = B3q[co];
#pragma unroll
        for (int x = 0; x < 6; ++x) {
            float m = fmaxf(fmaxf(acc0[2 * x], acc0[2 * x + 1]),
                            fmaxf(acc1[2 * x], acc1[2 * x + 1]));
            float v = fmaxf(m + bias, 0.0f);
            float q = rintf(v / st3);
            q = fminf(fmaxf(q, 0.0f), 15.0f);
            A3f[(co * 18 + r) * 20 + 6 * th + x] = q * st3;
        }
    }
    __syncthreads();

    // ---- phase 2: stage4 [18,18,18]->[18,8,8] into transposed O4t ----
    {
        const float st = s4[0] / 15.0f;
        for (int o = tid; o < 1152; o += 1024) {
            const int co = o >> 6;
            const int r  = (o >> 3) & 7;
            const int x  = o & 7;
            float a00 = 0.f, a01 = 0.f, a10 = 0.f, a11 = 0.f;
            for (int c = 0; c < 18; ++c) {
                float win[4][4];
#pragma unroll
                for (int rr = 0; rr < 4; ++rr) {
                    const int base = (c * 18 + 2 * r + rr) * 20 + 2 * x;
                    *(float2*)&win[rr][0] = *(const float2*)&A3f[base];
                    *(float2*)&win[rr][2] = *(const float2*)&A3f[base + 2];
                }
                const float* wp = &W4q[(co * 18 + c) * 9];
#pragma unroll
                for (int kr = 0; kr < 3; ++kr)
#pragma unroll
                    for (int kc = 0; kc < 3; ++kc) {
                        const float wvv = wp[kr * 3 + kc];
                        a00 = fmaf(win[kr    ][kc    ], wvv, a00);
                        a01 = fmaf(win[kr    ][kc + 1], wvv, a01);
                        a10 = fmaf(win[kr + 1][kc    ], wvv, a10);
                        a11 = fmaf(win[kr + 1][kc + 1], wvv, a11);
                    }
            }
            float m = fmaxf(fmaxf(a00, a01), fmaxf(a10, a11));
            float v = fmaxf(m + B4q[co], 0.0f);
            float q = rintf(v / st);
            q = fminf(fmaxf(q, 0.0f), 15.0f);
            O4t[(r * 8 + x) * 19 + co] = q * st;
        }
    }
    __syncthreads();

    // ---- phase 3: stage5 [18,8,8]->[18,3,3] = A5[162] ----
    {
        const float st = s5[0] / 15.0f;
        if (tid < 162) {
            const int co  = tid / 9;
            const int rem = tid - co * 9;
            const int r   = rem / 3;
            const int x   = rem - r * 3;
            float a00 = 0.f, a01 = 0.f, a10 = 0.f, a11 = 0.f;
            for (int c = 0; c < 18; ++c) {
                float win[4][4];
#pragma unroll
                for (int rr = 0; rr < 4; ++rr)
#pragma unroll
                    for (int cc = 0; cc < 4; ++cc)
                        win[rr][cc] = O4t[((2 * r + rr) * 8 + 2 * x + cc) * 19 + c];
                const float* wp = &W5q[(co * 18 + c) * 9];
#pragma unroll
                for (int kr = 0; kr < 3; ++kr)
#pragma unroll
                    for (int kc = 0; kc < 3; ++kc) {
                        const float wvv = wp[kr * 3 + kc];
                        a00 = fmaf(win[kr    ][kc    ], wvv, a00);
                        a01 = fmaf(win[kr    ][kc + 1], wvv, a01);
                        a10 = fmaf(win[kr + 1][kc    ], wvv, a10);
                        a11 = fmaf(win[kr + 1][kc + 1], wvv, a11);
                    }
            }
            float m = fmaxf(fmaxf(a00, a01), fmaxf(a10, a11));
            float v = fmaxf(m + B5q[co], 0.0f);
            float q = rintf(v / st);
            q = fminf(fmaxf(q, 0.0f), 15.0f);
            A5[tid] = q * st;
        }
    }
    __syncthreads();

    // ---- fc1: [162]->[120], split-k over 8 chunks, on-the-fly quant ----
    if (tid < 960) {
        const int m  = tid % 120;
        const int ch = tid / 120;
        const int k0 = 21 * ch;
        const int k1 = (ch == 7) ? 162 : k0 + 21;
        float p = 0.f;
        const float* wr = fw1 + (size_t)m * 162;
        for (int k = k0; k < k1; ++k) {
            float q = rintf(wr[k] / sf1);
            q = fminf(fmaxf(q, -3.f), 3.f);
            p = fmaf(A5[k], q * sf1, p);
        }
        part[ch][m] = p;
    }
    __syncthreads();
    if (tid < 120) {
        float acc = part[0][tid];
#pragma unroll
        for (int ch = 1; ch < 8; ++ch) acc += part[ch][tid];
        const float sb = sf1 * (s5[0] / 15.0f);
        acc += rintf(fb1[tid] / sb) * sb;
        const float st = s6[0] / 15.0f;
        float q = rintf(fmaxf(acc, 0.0f) / st);
        q = fminf(fmaxf(q, 0.0f), 15.0f);
        A6[tid] = q * st;
    }
    __syncthreads();

    // ---- fc2: [120]->[84], split-k over 8 chunks of 15 ----
    if (tid < 672) {
        const int m  = tid % 84;
        const int ch = tid / 84;
        const int k0 = 15 * ch;
        float p = 0.f;
        const float* wr = fw2 + (size_t)m * 120;
        for (int k = k0; k < k0 + 15; ++k) {
            float q = rintf(wr[k] / sf2);
            q = fminf(fmaxf(q, -3.f), 3.f);
            p = fmaf(A6[k], q * sf2, p);
        }
        part[ch][m] = p;
    }
    __syncthreads();
    if (tid < 84) {
        float acc = part[0][tid];
#pragma unroll
        for (int ch = 1; ch < 8; ++ch) acc += part[ch][tid];
        const float sb = sf2 * (s6[0] / 15.0f);
        acc += rintf(fb2[tid] / sb) * sb;
        const float st = s7[0] / 15.0f;
        float q = rintf(fmaxf(acc, 0.0f) / st);
        q = fminf(fmaxf(q, 0.0f), 15.0f);
        A7[tid] = q * st;
    }
    __syncthreads();

    // ---- fc3: [9 x 84], split-k over 7 chunks of 12 ----
    if (tid < 63) {
        const int m  = tid % 9;
        const int ch = tid / 9;
        const int k0 = 12 * ch;
        float p = 0.f;
        const float* wr = fw3 + (size_t)m * 84;
        for (int k = k0; k < k0 + 12; ++k) {
            float q = rintf(wr[k] / sf3);
            q = fminf(fmaxf(q, -3.f), 3.f);
            p = fmaf(A7[k], q * sf3, p);
        }
        part[ch][m] = p;
    }
    __syncthreads();
    if (tid < 9) {
        float acc = part[0][tid];
#pragma unroll
        for (int ch = 1; ch < 7; ++ch) acc += part[ch][tid];
        out[(size_t)n * 9 + tid] = acc;
    }
}

// ---------------------------------------------------------------------------
extern "C" void kernel_launch(void* const* d_in, const int* in_sizes, int n_in,
                              void* d_out, int out_size, void* d_ws, size_t ws_size,
                              hipStream_t stream)
{
    const float* x   = (const float*)d_in[0];
    const float* w1  = (const float*)d_in[1];
    const float* w2  = (const float*)d_in[2];
    const float* b2  = (const float*)d_in[3];
    const float* w3  = (const float*)d_in[4];
    const float* b3  = (const float*)d_in[5];
    const float* w4  = (const float*)d_in[6];
    const float* b4  = (const float*)d_in[7];
    const float* w5  = (const float*)d_in[8];
    const float* b5  = (const float*)d_in[9];
    const float* fw1 = (const float*)d_in[10];
    const float* fb1 = (const float*)d_in[11];
    const float* fw2 = (const float*)d_in[12];
    const float* fb2 = (const float*)d_in[13];
    const float* fw3 = (const float*)d_in[14];
    const float* s1  = (const float*)d_in[15];
    const float* s2  = (const float*)d_in[16];
    const float* s3  = (const float*)d_in[17];
    const float* s4  = (const float*)d_in[18];
    const float* s5  = (const float*)d_in[19];
    const float* s6  = (const float*)d_in[20];
    const float* s7  = (const float*)d_in[21];

    unsigned char* wsb = (unsigned char*)d_ws;
    float* out = (float*)d_out;

    // stage 1: f32 in -> u8 levels out [256][6][79][80]
    conv_stage<3, 6, 2, 160, 160, 79, 79, 80, 20, 4, 256, false, false>
        <<<dim3(20, 256), 256, 0, stream>>>(x, w1, nullptr, nullptr, s1,
                                            wsb + OFF_OUT1B);

    // stage 2: u8 in -> u8 levels out [256][12][38][40]
    conv_stage<6, 12, 2, 79, 80, 38, 38, 40, 10, 4, 256, true, true>
        <<<dim3(10, 256), 256, 0, stream>>>(wsb + OFF_OUT1B, w2, b2, s1, s2,
                                            wsb + OFF_OUT2B);

    // conv3 + stage4 + stage5 + fc1/fc2/fc3 in one kernel, 1 block / image
    tail_all<<<256, 1024, 0, stream>>>(wsb + OFF_OUT2B,
                                       w3, b3, w4, b4, w5, b5,
                                       fw1, fb1, fw2, fb2, fw3,
                                       s2, s3, s4, s5, s6, s7, out);
}

// Round 15
// 132.541 us; speedup vs baseline: 1.1376x; 1.0087x over previous
//
#include <hip/hip_runtime.h>
#include <hip/hip_bf16.h>
#include <math.h>
#include <type_traits>

// ---------------------------------------------------------------------------
// Workspace layout (byte offsets). Activations as u8 quant levels q in [0,15];
// f32 value reconstructed EXACTLY as (float)q * (s/15).
// ---------------------------------------------------------------------------
constexpr size_t OFF_OUT1B = 0;                          // u8 [256][6][79][80]
constexpr size_t OFF_OUT2B = (size_t)256 * 6 * 79 * 80;  // u8 [256][12][38][40]

// ---------------------------------------------------------------------------
// Fused conv3x3(VALID)[+bias]+quant_relu+maxpool2 (stages 1-2).
// Direct-global reads, 3-deep prefetch ring, in-kernel weight self-quant.
// Hot loop byte-identical to R12-R14; R15: RB=8 + 512-thread blocks
// (halved head replication, 8 waves/block).
// ---------------------------------------------------------------------------
template<int CIN, int COUT, int NCO, int HIN, int WSIN,
         int HPOOL, int WPOOL, int WSOUT, int XG, int RB,
         int THREADS, bool HAS_BIAS, bool IN_U8>
__global__ __launch_bounds__(THREADS)
void conv_stage(const void* __restrict__ in_,
                const float* __restrict__ w_raw,
                const float* __restrict__ b_raw,
                const float* __restrict__ s_prev,
                const float* __restrict__ s_act,
                unsigned char* __restrict__ out)
{
    using TIN = typename std::conditional<IN_U8, unsigned char, float>::type;
    constexpr int GROUPS = COUT / NCO;
    constexpr int W4IN   = WSIN / 4;
    constexpr int NW     = COUT * CIN * 9;
    constexpr int STEPS  = 4 * CIN;
    static_assert(NCO * GROUPS == COUT, "NCO divides COUT");
    static_assert(GROUPS * XG * RB <= THREADS, "single compute pass");
    static_assert(4 * XG == WSOUT, "full padded row coverage");
    static_assert(WSIN % 4 == 0, "vec4 loads");

    __shared__ float lw[NW];
    __shared__ float lb[COUT];
    __shared__ float red[THREADS];

    const int r0  = blockIdx.x * RB;
    const int n   = blockIdx.y;
    const int tid = threadIdx.x;

    float mx = 0.0f;
    for (int i = tid; i < NW; i += THREADS) {
        const float v = w_raw[i];
        lw[i] = v;
        mx = fmaxf(mx, fabsf(v));
    }
    if (HAS_BIAS)
        for (int i = tid; i < COUT; i += THREADS) lb[i] = b_raw[i];
    red[tid] = mx;
    __syncthreads();
    for (int s = THREADS / 2; s > 0; s >>= 1) {
        if (tid < s) red[tid] = fmaxf(red[tid], red[tid + s]);
        __syncthreads();
    }
    const float sw_ = red[0] / 3.0f;
    for (int i = tid; i < NW; i += THREADS) {
        float q = rintf(lw[i] / sw_);
        q = fminf(fmaxf(q, -3.0f), 3.0f);
        lw[i] = q * sw_;
    }
    if (HAS_BIAS) {
        const float sb = sw_ * (s_prev[0] / 15.0f);
        for (int i = tid; i < COUT; i += THREADS)
            lb[i] = rintf(lb[i] / sb) * sb;
    }
    __syncthreads();

    const int o = tid;
    if (o >= GROUPS * XG * RB) return;
    const int cog = o % GROUPS;
    const int xg  = (o / GROUPS) % XG;
    const int ry  = o / (GROUPS * XG);
    const int r   = r0 + ry;
    if (r >= HPOOL) return;

    const float step = s_act[0] / 15.0f;
    float step_in = 0.0f;
    if constexpr (IN_U8) step_in = s_prev[0] / 15.0f;

    const int u0 = 2 * xg;
    const int u1 = 2 * xg + 1;
    const int u2 = (2 * xg + 2 < W4IN) ? (2 * xg + 2) : (W4IN - 1);

    const TIN* in   = (const TIN*)in_;
    const TIN* base = in + (size_t)n * CIN * HIN * WSIN + (size_t)(2 * r) * WSIN;

    float acc[NCO][16];
#pragma unroll
    for (int j = 0; j < NCO; ++j)
#pragma unroll
        for (int i = 0; i < 16; ++i) acc[j][i] = 0.0f;

    float4       fbuf[3][3];
    unsigned int ubuf[3][3];
    float        wv[NCO][9];

#define ISSUE_STEP(S)                                                          \
    {                                                                          \
        const TIN* rp = base + (size_t)((S) >> 2) * HIN * WSIN                 \
                             + (size_t)((S) & 3) * WSIN;                       \
        if constexpr (IN_U8) {                                                 \
            ubuf[(S) % 3][0] = *(const unsigned int*)&rp[4 * u0];              \
            ubuf[(S) % 3][1] = *(const unsigned int*)&rp[4 * u1];              \
            ubuf[(S) % 3][2] = *(const unsigned int*)&rp[4 * u2];              \
        } else {                                                               \
            fbuf[(S) % 3][0] = *(const float4*)&rp[4 * u0];                    \
            fbuf[(S) % 3][1] = *(const float4*)&rp[4 * u1];                    \
            fbuf[(S) % 3][2] = *(const float4*)&rp[4 * u2];                    \
        }                                                                      \
    }

    ISSUE_STEP(0);
    ISSUE_STEP(1);

#pragma unroll
    for (int s = 0; s < STEPS; ++s) {
        const int c  = s >> 2;
        const int rr = s & 3;

        if (s + 2 < STEPS) ISSUE_STEP(s + 2);

        if (rr == 0) {
#pragma unroll
            for (int j = 0; j < NCO; ++j)
#pragma unroll
                for (int k = 0; k < 9; ++k)
                    wv[j][k] = lw[((NCO * cog + j) * CIN + c) * 9 + k];
        }

        float row[12];
        if constexpr (IN_U8) {
#pragma unroll
            for (int k = 0; k < 3; ++k) {
                const unsigned int d = ubuf[s % 3][k];
#pragma unroll
                for (int b = 0; b < 4; ++b)
                    row[4 * k + b] = (float)((d >> (8 * b)) & 0xffu) * step_in;
            }
        } else {
            const float* rv = (const float*)fbuf[s % 3];
#pragma unroll
            for (int i = 0; i < 12; ++i) row[i] = rv[i];
        }

        if (rr < 3) {
#pragma unroll
            for (int j = 0; j < NCO; ++j)
#pragma unroll
                for (int kc = 0; kc < 3; ++kc)
#pragma unroll
                    for (int xx = 0; xx < 8; ++xx)
                        acc[j][xx] = fmaf(row[xx + kc], wv[j][rr * 3 + kc], acc[j][xx]);
        }
        if (rr >= 1) {
#pragma unroll
            for (int j = 0; j < NCO; ++j)
#pragma unroll
                for (int kc = 0; kc < 3; ++kc)
#pragma unroll
                    for (int xx = 0; xx < 8; ++xx)
                        acc[j][8 + xx] = fmaf(row[xx + kc], wv[j][(rr - 1) * 3 + kc], acc[j][8 + xx]);
        }
    }
#undef ISSUE_STEP

#pragma unroll
    for (int j = 0; j < NCO; ++j) {
        const int co = NCO * cog + j;
        const float bias = HAS_BIAS ? lb[co] : 0.0f;
        unsigned int pck = 0;
#pragma unroll
        for (int t = 0; t < 4; ++t) {
            float m = fmaxf(fmaxf(acc[j][2 * t], acc[j][2 * t + 1]),
                            fmaxf(acc[j][8 + 2 * t], acc[j][8 + 2 * t + 1]));
            float v = fmaxf(m + bias, 0.0f);
            float q = rintf(v / step);
            q = fminf(fmaxf(q, 0.0f), 15.0f);
            const unsigned int qi = (4 * xg + t < WPOOL) ? (unsigned int)q : 0u;
            pck |= qi << (8 * t);
        }
        *(unsigned int*)&out[(((size_t)n * COUT + co) * HPOOL + r) * WSOUT + 4 * xg] = pck;
    }
}

__device__ __forceinline__ float wave_max(float v) {
#pragma unroll
    for (int off = 32; off > 0; off >>= 1)
        v = fmaxf(v, __shfl_down(v, off));
    return v;
}

// ---------------------------------------------------------------------------
// tail_all: conv3 + stage4 + stage5 + fc1/fc2/fc3 in ONE kernel,
// one 1024-thread block per image. R15: stage5 split-c x6 (972 active lanes
// instead of 162; partials in dead A3f scratch, fixed-order reduce).
// ---------------------------------------------------------------------------
__global__ __launch_bounds__(1024)
void tail_all(const unsigned char* __restrict__ in2,   // u8 [256][12][38][40]
              const float* __restrict__ w3, const float* __restrict__ b3,
              const float* __restrict__ w4, const float* __restrict__ b4,
              const float* __restrict__ w5, const float* __restrict__ b5,
              const float* __restrict__ fw1, const float* __restrict__ fb1,
              const float* __restrict__ fw2, const float* __restrict__ fb2,
              const float* __restrict__ fw3,
              const float* __restrict__ s2, const float* __restrict__ s3,
              const float* __restrict__ s4, const float* __restrict__ s5,
              const float* __restrict__ s6, const float* __restrict__ s7,
              float* __restrict__ out)
{
    __shared__ float A3f[18 * 18 * 20];   // padded x-stride 20 (25.9 KB)
    __shared__ float W3q[1944], W4q[2916], W5q[2916];
    __shared__ float B3q[18], B4q[18], B5q[18];
    __shared__ float O4t[64 * 19 + 1];    // (r*8+x)*19 + co
    __shared__ float A5[162], A6[120], A7[84];
    __shared__ float part[8][120];
    __shared__ float sm[16][6];
    __shared__ float scales[6];

    const int n    = blockIdx.x;
    const int tid  = threadIdx.x;
    const int wid  = tid >> 6;
    const int lane = tid & 63;

    // ---- phase 0: weights to LDS + all max-abs scales (wave_max reduce) ----
    float m3 = 0.f, m4 = 0.f, m5 = 0.f, g1 = 0.f, g2 = 0.f, g3 = 0.f;
    for (int i = tid; i < 1944; i += 1024) { const float v = w3[i]; W3q[i] = v; m3 = fmaxf(m3, fabsf(v)); }
    for (int i = tid; i < 2916; i += 1024) { const float v = w4[i]; W4q[i] = v; m4 = fmaxf(m4, fabsf(v)); }
    for (int i = tid; i < 2916; i += 1024) { const float v = w5[i]; W5q[i] = v; m5 = fmaxf(m5, fabsf(v)); }
    {
        const float4* f1 = (const float4*)fw1;
        for (int i = tid; i < 4860; i += 1024) {
            const float4 v = f1[i];
            g1 = fmaxf(g1, fmaxf(fmaxf(fabsf(v.x), fabsf(v.y)), fmaxf(fabsf(v.z), fabsf(v.w))));
        }
        const float4* f2 = (const float4*)fw2;
        for (int i = tid; i < 2520; i += 1024) {
            const float4 v = f2[i];
            g2 = fmaxf(g2, fmaxf(fmaxf(fabsf(v.x), fabsf(v.y)), fmaxf(fabsf(v.z), fabsf(v.w))));
        }
        const float4* f3 = (const float4*)fw3;
        for (int i = tid; i < 189; i += 1024) {
            const float4 v = f3[i];
            g3 = fmaxf(g3, fmaxf(fmaxf(fabsf(v.x), fabsf(v.y)), fmaxf(fabsf(v.z), fabsf(v.w))));
        }
    }
    if (tid < 18) { B3q[tid] = b3[tid]; B4q[tid] = b4[tid]; B5q[tid] = b5[tid]; }
    m3 = wave_max(m3); m4 = wave_max(m4); m5 = wave_max(m5);
    g1 = wave_max(g1); g2 = wave_max(g2); g3 = wave_max(g3);
    if (lane == 0) {
        sm[wid][0] = m3; sm[wid][1] = m4; sm[wid][2] = m5;
        sm[wid][3] = g1; sm[wid][4] = g2; sm[wid][5] = g3;
    }
    __syncthreads();
    if (tid < 6) {
        float v = sm[0][tid];
#pragma unroll
        for (int w = 1; w < 16; ++w) v = fmaxf(v, sm[w][tid]);
        scales[tid] = v / 3.0f;
    }
    __syncthreads();
    const float sw3 = scales[0], sw4 = scales[1], sw5 = scales[2];
    const float sf1 = scales[3], sf2 = scales[4], sf3 = scales[5];

    for (int i = tid; i < 1944; i += 1024) { float q = rintf(W3q[i] / sw3); q = fminf(fmaxf(q, -3.f), 3.f); W3q[i] = q * sw3; }
    for (int i = tid; i < 2916; i += 1024) { float q = rintf(W4q[i] / sw4); q = fminf(fmaxf(q, -3.f), 3.f); W4q[i] = q * sw4; }
    for (int i = tid; i < 2916; i += 1024) { float q = rintf(W5q[i] / sw5); q = fminf(fmaxf(q, -3.f), 3.f); W5q[i] = q * sw5; }
    if (tid < 18) {
        const float sb3 = sw3 * (s2[0] / 15.0f); B3q[tid] = rintf(B3q[tid] / sb3) * sb3;
        const float sb4 = sw4 * (s3[0] / 15.0f); B4q[tid] = rintf(B4q[tid] / sb4) * sb4;
        const float sb5 = sw5 * (s4[0] / 15.0f); B5q[tid] = rintf(B5q[tid] / sb5) * sb5;
    }
    __syncthreads();

    // ---- phase 1: conv3 [12,38,38]->[18,18,18] straight into padded A3f ----
    if (tid < 972) {                       // 18 rows x 18 co x 3 thirds
        const int r  = tid / 54;
        const int rm = tid - r * 54;
        const int co = rm / 3;
        const int th = rm - co * 3;        // pooled x in [6*th, 6*th+6)

        const float step2 = s2[0] / 15.0f;
        const float st3   = s3[0] / 15.0f;
        const unsigned char* base = in2 + (size_t)n * 18240 + (size_t)(2 * r) * 40 + 12 * th;

        float acc0[12], acc1[12];
#pragma unroll
        for (int i = 0; i < 12; ++i) { acc0[i] = 0.f; acc1[i] = 0.f; }

        uint4 ub[2][4];                    // ping-pong: 4 rows x 16 bytes

#define LOADC(C, B)                                                            \
        {                                                                      \
            const unsigned char* cp = base + (size_t)(C) * 1520;               \
            _Pragma("unroll")                                                  \
            for (int rr = 0; rr < 4; ++rr)                                     \
                __builtin_memcpy(&ub[B][rr], cp + rr * 40, 16);                \
        }

        LOADC(0, 0);

#pragma unroll
        for (int c = 0; c < 12; ++c) {
            if (c + 1 < 12) LOADC(c + 1, (c + 1) & 1);

            float wv[9];
#pragma unroll
            for (int k = 0; k < 9; ++k) wv[k] = W3q[(co * 12 + c) * 9 + k];

#pragma unroll
            for (int rr = 0; rr < 4; ++rr) {
                const unsigned int* dp = (const unsigned int*)&ub[c & 1][rr];
                float row[16];
#pragma unroll
                for (int k = 0; k < 4; ++k) {
                    const unsigned int d = dp[k];
#pragma unroll
                    for (int b = 0; b < 4; ++b)
                        row[4 * k + b] = (float)((d >> (8 * b)) & 0xffu) * step2;
                }
                if (rr < 3) {
#pragma unroll
                    for (int kc = 0; kc < 3; ++kc)
#pragma unroll
                        for (int xx = 0; xx < 12; ++xx)
                            acc0[xx] = fmaf(row[xx + kc], wv[rr * 3 + kc], acc0[xx]);
                }
                if (rr >= 1) {
#pragma unroll
                    for (int kc = 0; kc < 3; ++kc)
#pragma unroll
                        for (int xx = 0; xx < 12; ++xx)
                            acc1[xx] = fmaf(row[xx + kc], wv[(rr - 1) * 3 + kc], acc1[xx]);
                }
            }
        }
#undef LOADC

        const float bias = B3q[co];
#pragma unroll
        for (int x = 0; x < 6; ++x) {
            float m = fmaxf(fmaxf(acc0[2 * x], acc0[2 * x + 1]),
                            fmaxf(acc1[2 * x], acc1[2 * x + 1]));
            float v = fmaxf(m + bias, 0.0f);
            float q = rintf(v / st3);
            q = fminf(fmaxf(q, 0.0f), 15.0f);
            A3f[(co * 18 + r) * 20 + 6 * th + x] = q * st3;
        }
    }
    __syncthreads();

    // ---- phase 2: stage4 [18,18,18]->[18,8,8] into transposed O4t ----
    {
        const float st = s4[0] / 15.0f;
        for (int o = tid; o < 1152; o += 1024) {
            const int co = o >> 6;
            const int r  = (o >> 3) & 7;
            const int x  = o & 7;
            float a00 = 0.f, a01 = 0.f, a10 = 0.f, a11 = 0.f;
            for (int c = 0; c < 18; ++c) {
                float win[4][4];
#pragma unroll
                for (int rr = 0; rr < 4; ++rr) {
                    const int base = (c * 18 + 2 * r + rr) * 20 + 2 * x;
                    *(float2*)&win[rr][0] = *(const float2*)&A3f[base];
                    *(float2*)&win[rr][2] = *(const float2*)&A3f[base + 2];
                }
                const float* wp = &W4q[(co * 18 + c) * 9];
#pragma unroll
                for (int kr = 0; kr < 3; ++kr)
#pragma unroll
                    for (int kc = 0; kc < 3; ++kc) {
                        const float wvv = wp[kr * 3 + kc];
                        a00 = fmaf(win[kr    ][kc    ], wvv, a00);
                        a01 = fmaf(win[kr    ][kc + 1], wvv, a01);
                        a10 = fmaf(win[kr + 1][kc    ], wvv, a10);
                        a11 = fmaf(win[kr + 1][kc + 1], wvv, a11);
                    }
            }
            float m = fmaxf(fmaxf(a00, a01), fmaxf(a10, a11));
            float v = fmaxf(m + B4q[co], 0.0f);
            float q = rintf(v / st);
            q = fminf(fmaxf(q, 0.0f), 15.0f);
            O4t[(r * 8 + x) * 19 + co] = q * st;
        }
    }
    __syncthreads();

    // ---- phase 3a: stage5 partials, split-c x6 (972 lanes). Partials for
    // the 4 conv positions go into dead A3f scratch. ----
    {
        float* part5 = A3f;               // [6][162][4], 3888 <= 6480, dead now
        if (tid < 972) {
            const int outi = tid % 162;
            const int ch   = tid / 162;   // 0..5 -> channels 3ch..3ch+2
            const int co   = outi / 9;
            const int rem  = outi - co * 9;
            const int r    = rem / 3;
            const int x    = rem - r * 3;
            float a00 = 0.f, a01 = 0.f, a10 = 0.f, a11 = 0.f;
#pragma unroll
            for (int cc3 = 0; cc3 < 3; ++cc3) {
                const int c = 3 * ch + cc3;
                float win[4][4];
#pragma unroll
                for (int rr = 0; rr < 4; ++rr)
#pragma unroll
                    for (int cc = 0; cc < 4; ++cc)
                        win[rr][cc] = O4t[((2 * r + rr) * 8 + 2 * x + cc) * 19 + c];
                const float* wp = &W5q[(co * 18 + c) * 9];
#pragma unroll
                for (int kr = 0; kr < 3; ++kr)
#pragma unroll
                    for (int kc = 0; kc < 3; ++kc) {
                        const float wvv = wp[kr * 3 + kc];
                        a00 = fmaf(win[kr    ][kc    ], wvv, a00);
                        a01 = fmaf(win[kr    ][kc + 1], wvv, a01);
                        a10 = fmaf(win[kr + 1][kc    ], wvv, a10);
                        a11 = fmaf(win[kr + 1][kc + 1], wvv, a11);
                    }
            }
            float* p = &part5[(ch * 162 + outi) * 4];
            p[0] = a00; p[1] = a01; p[2] = a10; p[3] = a11;
        }
    }
    __syncthreads();

    // ---- phase 3b: stage5 reduce (fixed chunk order) -> A5[162] ----
    {
        const float* part5 = A3f;
        const float st = s5[0] / 15.0f;
        if (tid < 162) {
            float a[4];
#pragma unroll
            for (int j = 0; j < 4; ++j) a[j] = part5[(0 * 162 + tid) * 4 + j];
#pragma unroll
            for (int ch = 1; ch < 6; ++ch)
#pragma unroll
                for (int j = 0; j < 4; ++j) a[j] += part5[(ch * 162 + tid) * 4 + j];
            const int co = tid / 9;
            float m = fmaxf(fmaxf(a[0], a[1]), fmaxf(a[2], a[3]));
            float v = fmaxf(m + B5q[co], 0.0f);
            float q = rintf(v / st);
            q = fminf(fmaxf(q, 0.0f), 15.0f);
            A5[tid] = q * st;
        }
    }
    __syncthreads();

    // ---- fc1: [162]->[120], split-k over 8 chunks, on-the-fly quant ----
    if (tid < 960) {
        const int m  = tid % 120;
        const int ch = tid / 120;
        const int k0 = 21 * ch;
        const int k1 = (ch == 7) ? 162 : k0 + 21;
        float p = 0.f;
        const float* wr = fw1 + (size_t)m * 162;
        for (int k = k0; k < k1; ++k) {
            float q = rintf(wr[k] / sf1);
            q = fminf(fmaxf(q, -3.f), 3.f);
            p = fmaf(A5[k], q * sf1, p);
        }
        part[ch][m] = p;
    }
    __syncthreads();
    if (tid < 120) {
        float acc = part[0][tid];
#pragma unroll
        for (int ch = 1; ch < 8; ++ch) acc += part[ch][tid];
        const float sb = sf1 * (s5[0] / 15.0f);
        acc += rintf(fb1[tid] / sb) * sb;
        const float st = s6[0] / 15.0f;
        float q = rintf(fmaxf(acc, 0.0f) / st);
        q = fminf(fmaxf(q, 0.0f), 15.0f);
        A6[tid] = q * st;
    }
    __syncthreads();

    // ---- fc2: [120]->[84], split-k over 8 chunks of 15 ----
    if (tid < 672) {
        const int m  = tid % 84;
        const int ch = tid / 84;
        const int k0 = 15 * ch;
        float p = 0.f;
        const float* wr = fw2 + (size_t)m * 120;
        for (int k = k0; k < k0 + 15; ++k) {
            float q = rintf(wr[k] / sf2);
            q = fminf(fmaxf(q, -3.f), 3.f);
            p = fmaf(A6[k], q * sf2, p);
        }
        part[ch][m] = p;
    }
    __syncthreads();
    if (tid < 84) {
        float acc = part[0][tid];
#pragma unroll
        for (int ch = 1; ch < 8; ++ch) acc += part[ch][tid];
        const float sb = sf2 * (s6[0] / 15.0f);
        acc += rintf(fb2[tid] / sb) * sb;
        const float st = s7[0] / 15.0f;
        float q = rintf(fmaxf(acc, 0.0f) / st);
        q = fminf(fmaxf(q, 0.0f), 15.0f);
        A7[tid] = q * st;
    }
    __syncthreads();

    // ---- fc3: [9 x 84], split-k over 7 chunks of 12 ----
    if (tid < 63) {
        const int m  = tid % 9;
        const int ch = tid / 9;
        const int k0 = 12 * ch;
        float p = 0.f;
        const float* wr = fw3 + (size_t)m * 84;
        for (int k = k0; k < k0 + 12; ++k) {
            float q = rintf(wr[k] / sf3);
            q = fminf(fmaxf(q, -3.f), 3.f);
            p = fmaf(A7[k], q * sf3, p);
        }
        part[ch][m] = p;
    }
    __syncthreads();
    if (tid < 9) {
        float acc = part[0][tid];
#pragma unroll
        for (int ch = 1; ch < 7; ++ch) acc += part[ch][tid];
        out[(size_t)n * 9 + tid] = acc;
    }
}

// ---------------------------------------------------------------------------
extern "C" void kernel_launch(void* const* d_in, const int* in_sizes, int n_in,
                              void* d_out, int out_size, void* d_ws, size_t ws_size,
                              hipStream_t stream)
{
    const float* x   = (const float*)d_in[0];
    const float* w1  = (const float*)d_in[1];
    const float* w2  = (const float*)d_in[2];
    const float* b2  = (const float*)d_in[3];
    const float* w3  = (const float*)d_in[4];
    const float* b3  = (const float*)d_in[5];
    const float* w4  = (const float*)d_in[6];
    const float* b4  = (const float*)d_in[7];
    const float* w5  = (const float*)d_in[8];
    const float* b5  = (const float*)d_in[9];
    const float* fw1 = (const float*)d_in[10];
    const float* fb1 = (const float*)d_in[11];
    const float* fw2 = (const float*)d_in[12];
    const float* fb2 = (const float*)d_in[13];
    const float* fw3 = (const float*)d_in[14];
    const float* s1  = (const float*)d_in[15];
    const float* s2  = (const float*)d_in[16];
    const float* s3  = (const float*)d_in[17];
    const float* s4  = (const float*)d_in[18];
    const float* s5  = (const float*)d_in[19];
    const float* s6  = (const float*)d_in[20];
    const float* s7  = (const float*)d_in[21];

    unsigned char* wsb = (unsigned char*)d_ws;
    float* out = (float*)d_out;

    // stage 1: f32 in -> u8 levels out [256][6][79][80]; RB=8, 512 thr
    conv_stage<3, 6, 2, 160, 160, 79, 79, 80, 20, 8, 512, false, false>
        <<<dim3(10, 256), 512, 0, stream>>>(x, w1, nullptr, nullptr, s1,
                                            wsb + OFF_OUT1B);

    // stage 2: u8 in -> u8 levels out [256][12][38][40]; RB=8, 512 thr
    conv_stage<6, 12, 2, 79, 80, 38, 38, 40, 10, 8, 512, true, true>
        <<<dim3(5, 256), 512, 0, stream>>>(wsb + OFF_OUT1B, w2, b2, s1, s2,
                                           wsb + OFF_OUT2B);

    // conv3 + stage4 + stage5 + fc1/fc2/fc3 in one kernel, 1 block / image
    tail_all<<<256, 1024, 0, stream>>>(wsb + OFF_OUT2B,
                                       w3, b3, w4, b4, w5, b5,
                                       fw1, fb1, fw2, fb2, fw3,
                                       s2, s3, s4, s5, s6, s7, out);
}

// Round 16
// 127.234 us; speedup vs baseline: 1.1851x; 1.0417x over previous
//
#include <hip/hip_runtime.h>
#include <hip/hip_bf16.h>
#include <math.h>
#include <type_traits>

// ---------------------------------------------------------------------------
// Workspace layout (byte offsets). Activations as u8 quant levels q in [0,15];
// f32 value reconstructed EXACTLY as (float)q * (s/15). R16: the activation
// step is FOLDED INTO THE LDS WEIGHTS (acc = sum q*(w*step)), so the hot
// loops consume raw u8 levels via v_cvt_f32_ubyteN with no per-element mul.
// ---------------------------------------------------------------------------
constexpr size_t OFF_OUT1B = 0;                          // u8 [256][6][79][80]
constexpr size_t OFF_OUT2B = (size_t)256 * 6 * 79 * 80;  // u8 [256][12][38][40]

// ---------------------------------------------------------------------------
// Fused conv3x3(VALID)[+bias]+quant_relu+maxpool2 (stages 1-2).
// Direct-global reads, 3-deep prefetch ring, in-kernel weight self-quant.
// R16 (IN_U8 only): lw folded by step_in; row dequant = cvt only.
// ---------------------------------------------------------------------------
template<int CIN, int COUT, int NCO, int HIN, int WSIN,
         int HPOOL, int WPOOL, int WSOUT, int XG, int RB,
         int THREADS, bool HAS_BIAS, bool IN_U8>
__global__ __launch_bounds__(THREADS)
void conv_stage(const void* __restrict__ in_,
                const float* __restrict__ w_raw,
                const float* __restrict__ b_raw,
                const float* __restrict__ s_prev,
                const float* __restrict__ s_act,
                unsigned char* __restrict__ out)
{
    using TIN = typename std::conditional<IN_U8, unsigned char, float>::type;
    constexpr int GROUPS = COUT / NCO;
    constexpr int W4IN   = WSIN / 4;
    constexpr int NW     = COUT * CIN * 9;
    constexpr int STEPS  = 4 * CIN;
    static_assert(NCO * GROUPS == COUT, "NCO divides COUT");
    static_assert(GROUPS * XG * RB <= THREADS, "single compute pass");
    static_assert(4 * XG == WSOUT, "full padded row coverage");
    static_assert(WSIN % 4 == 0, "vec4 loads");

    __shared__ float lw[NW];
    __shared__ float lb[COUT];
    __shared__ float red[THREADS];

    const int r0  = blockIdx.x * RB;
    const int n   = blockIdx.y;
    const int tid = threadIdx.x;

    float mx = 0.0f;
    for (int i = tid; i < NW; i += THREADS) {
        const float v = w_raw[i];
        lw[i] = v;
        mx = fmaxf(mx, fabsf(v));
    }
    if (HAS_BIAS)
        for (int i = tid; i < COUT; i += THREADS) lb[i] = b_raw[i];
    red[tid] = mx;
    __syncthreads();
    for (int s = THREADS / 2; s > 0; s >>= 1) {
        if (tid < s) red[tid] = fmaxf(red[tid], red[tid + s]);
        __syncthreads();
    }
    const float sw_ = red[0] / 3.0f;
    float stepin_w = 1.0f;
    if constexpr (IN_U8) stepin_w = s_prev[0] / 15.0f;
    for (int i = tid; i < NW; i += THREADS) {
        float q = rintf(lw[i] / sw_);
        q = fminf(fmaxf(q, -3.0f), 3.0f);
        if constexpr (IN_U8)
            lw[i] = (q * sw_) * stepin_w;   // fold activation step into weight
        else
            lw[i] = q * sw_;
    }
    if (HAS_BIAS) {
        const float sb = sw_ * (s_prev[0] / 15.0f);
        for (int i = tid; i < COUT; i += THREADS)
            lb[i] = rintf(lb[i] / sb) * sb;
    }
    __syncthreads();

    const int o = tid;
    if (o >= GROUPS * XG * RB) return;
    const int cog = o % GROUPS;
    const int xg  = (o / GROUPS) % XG;
    const int ry  = o / (GROUPS * XG);
    const int r   = r0 + ry;
    if (r >= HPOOL) return;

    const float step = s_act[0] / 15.0f;

    const int u0 = 2 * xg;
    const int u1 = 2 * xg + 1;
    const int u2 = (2 * xg + 2 < W4IN) ? (2 * xg + 2) : (W4IN - 1);

    const TIN* in   = (const TIN*)in_;
    const TIN* base = in + (size_t)n * CIN * HIN * WSIN + (size_t)(2 * r) * WSIN;

    float acc[NCO][16];
#pragma unroll
    for (int j = 0; j < NCO; ++j)
#pragma unroll
        for (int i = 0; i < 16; ++i) acc[j][i] = 0.0f;

    float4       fbuf[3][3];
    unsigned int ubuf[3][3];
    float        wv[NCO][9];

#define ISSUE_STEP(S)                                                          \
    {                                                                          \
        const TIN* rp = base + (size_t)((S) >> 2) * HIN * WSIN                 \
                             + (size_t)((S) & 3) * WSIN;                       \
        if constexpr (IN_U8) {                                                 \
            ubuf[(S) % 3][0] = *(const unsigned int*)&rp[4 * u0];              \
            ubuf[(S) % 3][1] = *(const unsigned int*)&rp[4 * u1];              \
            ubuf[(S) % 3][2] = *(const unsigned int*)&rp[4 * u2];              \
        } else {                                                               \
            fbuf[(S) % 3][0] = *(const float4*)&rp[4 * u0];                    \
            fbuf[(S) % 3][1] = *(const float4*)&rp[4 * u1];                    \
            fbuf[(S) % 3][2] = *(const float4*)&rp[4 * u2];                    \
        }                                                                      \
    }

    ISSUE_STEP(0);
    ISSUE_STEP(1);

#pragma unroll
    for (int s = 0; s < STEPS; ++s) {
        const int c  = s >> 2;
        const int rr = s & 3;

        if (s + 2 < STEPS) ISSUE_STEP(s + 2);

        if (rr == 0) {
#pragma unroll
            for (int j = 0; j < NCO; ++j)
#pragma unroll
                for (int k = 0; k < 9; ++k)
                    wv[j][k] = lw[((NCO * cog + j) * CIN + c) * 9 + k];
        }

        float row[12];
        if constexpr (IN_U8) {
#pragma unroll
            for (int k = 0; k < 3; ++k) {
                const unsigned int d = ubuf[s % 3][k];
#pragma unroll
                for (int b = 0; b < 4; ++b)
                    row[4 * k + b] = (float)((d >> (8 * b)) & 0xffu);  // cvt only
            }
        } else {
            const float* rv = (const float*)fbuf[s % 3];
#pragma unroll
            for (int i = 0; i < 12; ++i) row[i] = rv[i];
        }

        if (rr < 3) {
#pragma unroll
            for (int j = 0; j < NCO; ++j)
#pragma unroll
                for (int kc = 0; kc < 3; ++kc)
#pragma unroll
                    for (int xx = 0; xx < 8; ++xx)
                        acc[j][xx] = fmaf(row[xx + kc], wv[j][rr * 3 + kc], acc[j][xx]);
        }
        if (rr >= 1) {
#pragma unroll
            for (int j = 0; j < NCO; ++j)
#pragma unroll
                for (int kc = 0; kc < 3; ++kc)
#pragma unroll
                    for (int xx = 0; xx < 8; ++xx)
                        acc[j][8 + xx] = fmaf(row[xx + kc], wv[j][(rr - 1) * 3 + kc], acc[j][8 + xx]);
        }
    }
#undef ISSUE_STEP

#pragma unroll
    for (int j = 0; j < NCO; ++j) {
        const int co = NCO * cog + j;
        const float bias = HAS_BIAS ? lb[co] : 0.0f;
        unsigned int pck = 0;
#pragma unroll
        for (int t = 0; t < 4; ++t) {
            float m = fmaxf(fmaxf(acc[j][2 * t], acc[j][2 * t + 1]),
                            fmaxf(acc[j][8 + 2 * t], acc[j][8 + 2 * t + 1]));
            float v = fmaxf(m + bias, 0.0f);
            float q = rintf(v / step);
            q = fminf(fmaxf(q, 0.0f), 15.0f);
            const unsigned int qi = (4 * xg + t < WPOOL) ? (unsigned int)q : 0u;
            pck |= qi << (8 * t);
        }
        *(unsigned int*)&out[(((size_t)n * COUT + co) * HPOOL + r) * WSOUT + 4 * xg] = pck;
    }
}

__device__ __forceinline__ float wave_max(float v) {
#pragma unroll
    for (int off = 32; off > 0; off >>= 1)
        v = fmaxf(v, __shfl_down(v, off));
    return v;
}

// ---------------------------------------------------------------------------
// tail_all: conv3 + stage4 + stage5 + fc1/fc2/fc3 in ONE kernel,
// one 1024-thread block per image. R16: W3q folded by step2 (phase-1 dequant
// = cvt only). Stage5 split-c x6; O4t stride 19; A3f stride 20; split-k FCs.
// ---------------------------------------------------------------------------
__global__ __launch_bounds__(1024)
void tail_all(const unsigned char* __restrict__ in2,   // u8 [256][12][38][40]
              const float* __restrict__ w3, const float* __restrict__ b3,
              const float* __restrict__ w4, const float* __restrict__ b4,
              const float* __restrict__ w5, const float* __restrict__ b5,
              const float* __restrict__ fw1, const float* __restrict__ fb1,
              const float* __restrict__ fw2, const float* __restrict__ fb2,
              const float* __restrict__ fw3,
              const float* __restrict__ s2, const float* __restrict__ s3,
              const float* __restrict__ s4, const float* __restrict__ s5,
              const float* __restrict__ s6, const float* __restrict__ s7,
              float* __restrict__ out)
{
    __shared__ float A3f[18 * 18 * 20];   // padded x-stride 20 (25.9 KB)
    __shared__ float W3q[1944], W4q[2916], W5q[2916];
    __shared__ float B3q[18], B4q[18], B5q[18];
    __shared__ float O4t[64 * 19 + 1];    // (r*8+x)*19 + co
    __shared__ float A5[162], A6[120], A7[84];
    __shared__ float part[8][120];
    __shared__ float sm[16][6];
    __shared__ float scales[6];

    const int n    = blockIdx.x;
    const int tid  = threadIdx.x;
    const int wid  = tid >> 6;
    const int lane = tid & 63;

    // ---- phase 0: weights to LDS + all max-abs scales (wave_max reduce) ----
    float m3 = 0.f, m4 = 0.f, m5 = 0.f, g1 = 0.f, g2 = 0.f, g3 = 0.f;
    for (int i = tid; i < 1944; i += 1024) { const float v = w3[i]; W3q[i] = v; m3 = fmaxf(m3, fabsf(v)); }
    for (int i = tid; i < 2916; i += 1024) { const float v = w4[i]; W4q[i] = v; m4 = fmaxf(m4, fabsf(v)); }
    for (int i = tid; i < 2916; i += 1024) { const float v = w5[i]; W5q[i] = v; m5 = fmaxf(m5, fabsf(v)); }
    {
        const float4* f1 = (const float4*)fw1;
        for (int i = tid; i < 4860; i += 1024) {
            const float4 v = f1[i];
            g1 = fmaxf(g1, fmaxf(fmaxf(fabsf(v.x), fabsf(v.y)), fmaxf(fabsf(v.z), fabsf(v.w))));
        }
        const float4* f2 = (const float4*)fw2;
        for (int i = tid; i < 2520; i += 1024) {
            const float4 v = f2[i];
            g2 = fmaxf(g2, fmaxf(fmaxf(fabsf(v.x), fabsf(v.y)), fmaxf(fabsf(v.z), fabsf(v.w))));
        }
        const float4* f3 = (const float4*)fw3;
        for (int i = tid; i < 189; i += 1024) {
            const float4 v = f3[i];
            g3 = fmaxf(g3, fmaxf(fmaxf(fabsf(v.x), fabsf(v.y)), fmaxf(fabsf(v.z), fabsf(v.w))));
        }
    }
    if (tid < 18) { B3q[tid] = b3[tid]; B4q[tid] = b4[tid]; B5q[tid] = b5[tid]; }
    m3 = wave_max(m3); m4 = wave_max(m4); m5 = wave_max(m5);
    g1 = wave_max(g1); g2 = wave_max(g2); g3 = wave_max(g3);
    if (lane == 0) {
        sm[wid][0] = m3; sm[wid][1] = m4; sm[wid][2] = m5;
        sm[wid][3] = g1; sm[wid][4] = g2; sm[wid][5] = g3;
    }
    __syncthreads();
    if (tid < 6) {
        float v = sm[0][tid];
#pragma unroll
        for (int w = 1; w < 16; ++w) v = fmaxf(v, sm[w][tid]);
        scales[tid] = v / 3.0f;
    }
    __syncthreads();
    const float sw3 = scales[0], sw4 = scales[1], sw5 = scales[2];
    const float sf1 = scales[3], sf2 = scales[4], sf3 = scales[5];

    const float step2f = s2[0] / 15.0f;
    for (int i = tid; i < 1944; i += 1024) {
        float q = rintf(W3q[i] / sw3); q = fminf(fmaxf(q, -3.f), 3.f);
        W3q[i] = (q * sw3) * step2f;      // fold activation step into weight
    }
    for (int i = tid; i < 2916; i += 1024) { float q = rintf(W4q[i] / sw4); q = fminf(fmaxf(q, -3.f), 3.f); W4q[i] = q * sw4; }
    for (int i = tid; i < 2916; i += 1024) { float q = rintf(W5q[i] / sw5); q = fminf(fmaxf(q, -3.f), 3.f); W5q[i] = q * sw5; }
    if (tid < 18) {
        const float sb3 = sw3 * (s2[0] / 15.0f); B3q[tid] = rintf(B3q[tid] / sb3) * sb3;
        const float sb4 = sw4 * (s3[0] / 15.0f); B4q[tid] = rintf(B4q[tid] / sb4) * sb4;
        const float sb5 = sw5 * (s4[0] / 15.0f); B5q[tid] = rintf(B5q[tid] / sb5) * sb5;
    }
    __syncthreads();

    // ---- phase 1: conv3 [12,38,38]->[18,18,18] straight into padded A3f ----
    if (tid < 972) {                       // 18 rows x 18 co x 3 thirds
        const int r  = tid / 54;
        const int rm = tid - r * 54;
        const int co = rm / 3;
        const int th = rm - co * 3;        // pooled x in [6*th, 6*th+6)

        const float st3 = s3[0] / 15.0f;
        const unsigned char* base = in2 + (size_t)n * 18240 + (size_t)(2 * r) * 40 + 12 * th;

        float acc0[12], acc1[12];
#pragma unroll
        for (int i = 0; i < 12; ++i) { acc0[i] = 0.f; acc1[i] = 0.f; }

        uint4 ub[2][4];                    // ping-pong: 4 rows x 16 bytes

#define LOADC(C, B)                                                            \
        {                                                                      \
            const unsigned char* cp = base + (size_t)(C) * 1520;               \
            _Pragma("unroll")                                                  \
            for (int rr = 0; rr < 4; ++rr)                                     \
                __builtin_memcpy(&ub[B][rr], cp + rr * 40, 16);                \
        }

        LOADC(0, 0);

#pragma unroll
        for (int c = 0; c < 12; ++c) {
            if (c + 1 < 12) LOADC(c + 1, (c + 1) & 1);

            float wv[9];
#pragma unroll
            for (int k = 0; k < 9; ++k) wv[k] = W3q[(co * 12 + c) * 9 + k];

#pragma unroll
            for (int rr = 0; rr < 4; ++rr) {
                const unsigned int* dp = (const unsigned int*)&ub[c & 1][rr];
                float row[16];
#pragma unroll
                for (int k = 0; k < 4; ++k) {
                    const unsigned int d = dp[k];
#pragma unroll
                    for (int b = 0; b < 4; ++b)
                        row[4 * k + b] = (float)((d >> (8 * b)) & 0xffu);  // cvt only
                }
                if (rr < 3) {
#pragma unroll
                    for (int kc = 0; kc < 3; ++kc)
#pragma unroll
                        for (int xx = 0; xx < 12; ++xx)
                            acc0[xx] = fmaf(row[xx + kc], wv[rr * 3 + kc], acc0[xx]);
                }
                if (rr >= 1) {
#pragma unroll
                    for (int kc = 0; kc < 3; ++kc)
#pragma unroll
                        for (int xx = 0; xx < 12; ++xx)
                            acc1[xx] = fmaf(row[xx + kc], wv[(rr - 1) * 3 + kc], acc1[xx]);
                }
            }
        }
#undef LOADC

        const float bias = B3q[co];
#pragma unroll
        for (int x = 0; x < 6; ++x) {
            float m = fmaxf(fmaxf(acc0[2 * x], acc0[2 * x + 1]),
                            fmaxf(acc1[2 * x], acc1[2 * x + 1]));
            float v = fmaxf(m + bias, 0.0f);
            float q = rintf(v / st3);
            q = fminf(fmaxf(q, 0.0f), 15.0f);
            A3f[(co * 18 + r) * 20 + 6 * th + x] = q * st3;
        }
    }
    __syncthreads();

    // ---- phase 2: stage4 [18,18,18]->[18,8,8] into transposed O4t ----
    {
        const float st = s4[0] / 15.0f;
        for (int o = tid; o < 1152; o += 1024) {
            const int co = o >> 6;
            const int r  = (o >> 3) & 7;
            const int x  = o & 7;
            float a00 = 0.f, a01 = 0.f, a10 = 0.f, a11 = 0.f;
            for (int c = 0; c < 18; ++c) {
                float win[4][4];
#pragma unroll
                for (int rr = 0; rr < 4; ++rr) {
                    const int base = (c * 18 + 2 * r + rr) * 20 + 2 * x;
                    *(float2*)&win[rr][0] = *(const float2*)&A3f[base];
                    *(float2*)&win[rr][2] = *(const float2*)&A3f[base + 2];
                }
                const float* wp = &W4q[(co * 18 + c) * 9];
#pragma unroll
                for (int kr = 0; kr < 3; ++kr)
#pragma unroll
                    for (int kc = 0; kc < 3; ++kc) {
                        const float wvv = wp[kr * 3 + kc];
                        a00 = fmaf(win[kr    ][kc    ], wvv, a00);
                        a01 = fmaf(win[kr    ][kc + 1], wvv, a01);
                        a10 = fmaf(win[kr + 1][kc    ], wvv, a10);
                        a11 = fmaf(win[kr + 1][kc + 1], wvv, a11);
                    }
            }
            float m = fmaxf(fmaxf(a00, a01), fmaxf(a10, a11));
            float v = fmaxf(m + B4q[co], 0.0f);
            float q = rintf(v / st);
            q = fminf(fmaxf(q, 0.0f), 15.0f);
            O4t[(r * 8 + x) * 19 + co] = q * st;
        }
    }
    __syncthreads();

    // ---- phase 3a: stage5 partials, split-c x6 (972 lanes) ----
    {
        float* part5 = A3f;               // [6][162][4], dead scratch
        if (tid < 972) {
            const int outi = tid % 162;
            const int ch   = tid / 162;   // 0..5 -> channels 3ch..3ch+2
            const int co   = outi / 9;
            const int rem  = outi - co * 9;
            const int r    = rem / 3;
            const int x    = rem - r * 3;
            float a00 = 0.f, a01 = 0.f, a10 = 0.f, a11 = 0.f;
#pragma unroll
            for (int cc3 = 0; cc3 < 3; ++cc3) {
                const int c = 3 * ch + cc3;
                float win[4][4];
#pragma unroll
                for (int rr = 0; rr < 4; ++rr)
#pragma unroll
                    for (int cc = 0; cc < 4; ++cc)
                        win[rr][cc] = O4t[((2 * r + rr) * 8 + 2 * x + cc) * 19 + c];
                const float* wp = &W5q[(co * 18 + c) * 9];
#pragma unroll
                for (int kr = 0; kr < 3; ++kr)
#pragma unroll
                    for (int kc = 0; kc < 3; ++kc) {
                        const float wvv = wp[kr * 3 + kc];
                        a00 = fmaf(win[kr    ][kc    ], wvv, a00);
                        a01 = fmaf(win[kr    ][kc + 1], wvv, a01);
                        a10 = fmaf(win[kr + 1][kc    ], wvv, a10);
                        a11 = fmaf(win[kr + 1][kc + 1], wvv, a11);
                    }
            }
            float* p = &part5[(ch * 162 + outi) * 4];
            p[0] = a00; p[1] = a01; p[2] = a10; p[3] = a11;
        }
    }
    __syncthreads();

    // ---- phase 3b: stage5 reduce -> A5[162] ----
    {
        const float* part5 = A3f;
        const float st = s5[0] / 15.0f;
        if (tid < 162) {
            float a[4];
#pragma unroll
            for (int j = 0; j < 4; ++j) a[j] = part5[(0 * 162 + tid) * 4 + j];
#pragma unroll
            for (int ch = 1; ch < 6; ++ch)
#pragma unroll
                for (int j = 0; j < 4; ++j) a[j] += part5[(ch * 162 + tid) * 4 + j];
            const int co = tid / 9;
            float m = fmaxf(fmaxf(a[0], a[1]), fmaxf(a[2], a[3]));
            float v = fmaxf(m + B5q[co], 0.0f);
            float q = rintf(v / st);
            q = fminf(fmaxf(q, 0.0f), 15.0f);
            A5[tid] = q * st;
        }
    }
    __syncthreads();

    // ---- fc1: [162]->[120], split-k over 8 chunks, on-the-fly quant ----
    if (tid < 960) {
        const int m  = tid % 120;
        const int ch = tid / 120;
        const int k0 = 21 * ch;
        const int k1 = (ch == 7) ? 162 : k0 + 21;
        float p = 0.f;
        const float* wr = fw1 + (size_t)m * 162;
        for (int k = k0; k < k1; ++k) {
            float q = rintf(wr[k] / sf1);
            q = fminf(fmaxf(q, -3.f), 3.f);
            p = fmaf(A5[k], q * sf1, p);
        }
        part[ch][m] = p;
    }
    __syncthreads();
    if (tid < 120) {
        float acc = part[0][tid];
#pragma unroll
        for (int ch = 1; ch < 8; ++ch) acc += part[ch][tid];
        const float sb = sf1 * (s5[0] / 15.0f);
        acc += rintf(fb1[tid] / sb) * sb;
        const float st = s6[0] / 15.0f;
        float q = rintf(fmaxf(acc, 0.0f) / st);
        q = fminf(fmaxf(q, 0.0f), 15.0f);
        A6[tid] = q * st;
    }
    __syncthreads();

    // ---- fc2: [120]->[84], split-k over 8 chunks of 15 ----
    if (tid < 672) {
        const int m  = tid % 84;
        const int ch = tid / 84;
        const int k0 = 15 * ch;
        float p = 0.f;
        const float* wr = fw2 + (size_t)m * 120;
        for (int k = k0; k < k0 + 15; ++k) {
            float q = rintf(wr[k] / sf2);
            q = fminf(fmaxf(q, -3.f), 3.f);
            p = fmaf(A6[k], q * sf2, p);
        }
        part[ch][m] = p;
    }
    __syncthreads();
    if (tid < 84) {
        float acc = part[0][tid];
#pragma unroll
        for (int ch = 1; ch < 8; ++ch) acc += part[ch][tid];
        const float sb = sf2 * (s6[0] / 15.0f);
        acc += rintf(fb2[tid] / sb) * sb;
        const float st = s7[0] / 15.0f;
        float q = rintf(fmaxf(acc, 0.0f) / st);
        q = fminf(fmaxf(q, 0.0f), 15.0f);
        A7[tid] = q * st;
    }
    __syncthreads();

    // ---- fc3: [9 x 84], split-k over 7 chunks of 12 ----
    if (tid < 63) {
        const int m  = tid % 9;
        const int ch = tid / 9;
        const int k0 = 12 * ch;
        float p = 0.f;
        const float* wr = fw3 + (size_t)m * 84;
        for (int k = k0; k < k0 + 12; ++k) {
            float q = rintf(wr[k] / sf3);
            q = fminf(fmaxf(q, -3.f), 3.f);
            p = fmaf(A7[k], q * sf3, p);
        }
        part[ch][m] = p;
    }
    __syncthreads();
    if (tid < 9) {
        float acc = part[0][tid];
#pragma unroll
        for (int ch = 1; ch < 7; ++ch) acc += part[ch][tid];
        out[(size_t)n * 9 + tid] = acc;
    }
}

// ---------------------------------------------------------------------------
extern "C" void kernel_launch(void* const* d_in, const int* in_sizes, int n_in,
                              void* d_out, int out_size, void* d_ws, size_t ws_size,
                              hipStream_t stream)
{
    const float* x   = (const float*)d_in[0];
    const float* w1  = (const float*)d_in[1];
    const float* w2  = (const float*)d_in[2];
    const float* b2  = (const float*)d_in[3];
    const float* w3  = (const float*)d_in[4];
    const float* b3  = (const float*)d_in[5];
    const float* w4  = (const float*)d_in[6];
    const float* b4  = (const float*)d_in[7];
    const float* w5  = (const float*)d_in[8];
    const float* b5  = (const float*)d_in[9];
    const float* fw1 = (const float*)d_in[10];
    const float* fb1 = (const float*)d_in[11];
    const float* fw2 = (const float*)d_in[12];
    const float* fb2 = (const float*)d_in[13];
    const float* fw3 = (const float*)d_in[14];
    const float* s1  = (const float*)d_in[15];
    const float* s2  = (const float*)d_in[16];
    const float* s3  = (const float*)d_in[17];
    const float* s4  = (const float*)d_in[18];
    const float* s5  = (const float*)d_in[19];
    const float* s6  = (const float*)d_in[20];
    const float* s7  = (const float*)d_in[21];

    unsigned char* wsb = (unsigned char*)d_ws;
    float* out = (float*)d_out;

    // stage 1: f32 in -> u8 levels out [256][6][79][80]; RB=8, 512 thr
    conv_stage<3, 6, 2, 160, 160, 79, 79, 80, 20, 8, 512, false, false>
        <<<dim3(10, 256), 512, 0, stream>>>(x, w1, nullptr, nullptr, s1,
                                            wsb + OFF_OUT1B);

    // stage 2: u8 in -> u8 levels out [256][12][38][40]; RB=8, 512 thr
    conv_stage<6, 12, 2, 79, 80, 38, 38, 40, 10, 8, 512, true, true>
        <<<dim3(5, 256), 512, 0, stream>>>(wsb + OFF_OUT1B, w2, b2, s1, s2,
                                           wsb + OFF_OUT2B);

    // conv3 + stage4 + stage5 + fc1/fc2/fc3 in one kernel, 1 block / image
    tail_all<<<256, 1024, 0, stream>>>(wsb + OFF_OUT2B,
                                       w3, b3, w4, b4, w5, b5,
                                       fw1, fb1, fw2, fb2, fw3,
                                       s2, s3, s4, s5, s6, s7, out);
}